// Round 6
// baseline (1141.462 us; speedup 1.0000x reference)
//
#include <hip/hip_runtime.h>
#include <math.h>

#define Bsz 64
#define Tt  32
#define Dv  2048
#define Hd  1024
#define G3  3072
#define Vv  20000
#define ML  3

typedef __attribute__((ext_vector_type(8))) short bf16x8;
typedef __attribute__((ext_vector_type(4))) float f32x4;
typedef unsigned long long u64;
#define MFMA(a,b,c) __builtin_amdgcn_mfma_f32_16x16x32_bf16(a,b,c,0,0,0)

__device__ __forceinline__ short f2bf(float f) {
    union { float f; unsigned u; } v; v.f = f;
    unsigned r = v.u + 0x7fffu + ((v.u >> 16) & 1u);
    return (short)(r >> 16);
}
__device__ __forceinline__ float bf2f(short s) {
    union { unsigned u; float f; } v; v.u = ((unsigned)(unsigned short)s) << 16;
    return v.f;
}

// ---------------------------------------------------------------------------
// fp32 -> bf16 conversion, 8 elems/thread, optional row slicing (for W_ih2).
// ---------------------------------------------------------------------------
__global__ __launch_bounds__(256)
void cvt_f32_bf16(const float* __restrict__ src, short* __restrict__ dst,
                  long total8, long cols8, int src_ld, int dst_ld)
{
    long i = (long)blockIdx.x * 256 + threadIdx.x;
    if (i >= total8) return;
    long r = i / cols8; long c = i - r * cols8;
    const float* s = src + r * (long)src_ld + c * 8;
    float4 x = *(const float4*)s;
    float4 y = *(const float4*)(s + 4);
    bf16x8 o;
    o[0]=f2bf(x.x); o[1]=f2bf(x.y); o[2]=f2bf(x.z); o[3]=f2bf(x.w);
    o[4]=f2bf(y.x); o[5]=f2bf(y.y); o[6]=f2bf(y.z); o[7]=f2bf(y.w);
    *(bf16x8*)(dst + r * (long)dst_ld + c * 8) = o;
}

// ---------------------------------------------------------------------------
// Big MFMA GEMM (unchanged): C[M,N] = A*W^T + bias, 128x128 tile.
// ---------------------------------------------------------------------------
__global__ __launch_bounds__(256)
void gemm_mfma_128(const short* __restrict__ A, int lda,
                   const short* __restrict__ W, int ldw,
                   const float* __restrict__ bias,
                   float* __restrict__ C, int ldc, int K)
{
    __shared__ __align__(16) short As[128 * 40];
    __shared__ __align__(16) short Bs[128 * 40];
    const int tid = threadIdx.x;
    const int w = tid >> 6, l = tid & 63;
    const int wm = w >> 1, wn = w & 1;
    const int lr = l & 15, lg = l >> 4;
    const int m0 = blockIdx.y * 128, n0 = blockIdx.x * 128;
    const int sm = tid >> 2;
    const int skg = tid & 3;

    f32x4 acc[4][4] = {};

    for (int k0 = 0; k0 < K; k0 += 32) {
        #pragma unroll
        for (int i = 0; i < 2; ++i) {
            const int m = i * 64 + sm;
            bf16x8 av = *(const bf16x8*)(A + (size_t)(m0 + m) * lda + k0 + skg * 8);
            bf16x8 wv = *(const bf16x8*)(W + (size_t)(n0 + m) * ldw + k0 + skg * 8);
            *(bf16x8*)(As + m * 40 + skg * 8) = av;
            *(bf16x8*)(Bs + m * 40 + skg * 8) = wv;
        }
        __syncthreads();
        bf16x8 af[4], bfr[4];
        #pragma unroll
        for (int mt = 0; mt < 4; ++mt) {
            const int m = wm * 64 + mt * 16 + lr;
            const int n = wn * 64 + mt * 16 + lr;
            af[mt]  = *(const bf16x8*)(As + m * 40 + lg * 8);
            bfr[mt] = *(const bf16x8*)(Bs + n * 40 + lg * 8);
        }
        #pragma unroll
        for (int mt = 0; mt < 4; ++mt)
            #pragma unroll
            for (int nt = 0; nt < 4; ++nt)
                acc[mt][nt] = MFMA(af[mt], bfr[nt], acc[mt][nt]);
        __syncthreads();
    }

    #pragma unroll
    for (int mt = 0; mt < 4; ++mt)
        #pragma unroll
        for (int nt = 0; nt < 4; ++nt)
            #pragma unroll
            for (int v = 0; v < 4; ++v) {
                const int m = m0 + wm * 64 + mt * 16 + lg * 4 + v;
                const int n = n0 + wn * 64 + nt * 16 + lr;
                C[(size_t)m * ldc + n] = acc[mt][nt][v] + bias[n];
            }
}

// ---------------------------------------------------------------------------
// Persistent GRU scan v4 — FENCE-FREE step synchronization.
//  - h exchanged ONLY via relaxed agent-scope atomic u64 ops (bypass L1/L2,
//    coherent at the coherence point -> no acquire/release fences, L2 for
//    W/xp is NEVER invalidated).
//  - flags[blk] = completed-step count, one relaxed atomic store per block;
//    consumers: each lane polls one flag, __all(f >= s) -> no RMW chains.
//    __syncthreads() before the flag store drains vmcnt, so all 256 threads'
//    h-stores are acked at the coherence point before the flag moves.
//  - W slice (48 rows x 1024) staged ONCE into LDS in MFMA-fragment-linear
//    order: read addr = base + lane*16B -> conflict-free by construction.
//  - h carried in f32 regs; xp prefetched for s+1 before the store phase.
// 64 blocks x 256 thr (4 waves); block owns 16 gate-cols j0=blk*16 (3 gates);
// wave w owns K-quarter; K-partials reduced via 48KB LDS xch.
// ---------------------------------------------------------------------------
__global__ __launch_bounds__(256, 1)
void gru_scan(const float* __restrict__ xp, int xp_rs, int xp_ts,
              const short* __restrict__ Whh,   // bf16 [3072][1024]
              const float* __restrict__ b_hh,
              short* __restrict__ hb0, short* __restrict__ hb1, int p0,
              short* __restrict__ out_seq,     // bf16 (T*64,1024) or null
              int T, unsigned int* __restrict__ flags)
{
    __shared__ __align__(16) short Wl[4 * 3 * 8 * 64 * 8];   // 98304 B frag-order
    __shared__ __align__(16) float xch[4][4][3][256];        // 49152 B
    __shared__ __align__(16) short hstage[64][16];           // 2048 B
    const int tid = threadIdx.x;
    const int w  = tid >> 6;          // K-quarter, also epilogue batch-tile
    const int l  = tid & 63;
    const int lr = l & 15, lg = l >> 4;
    const int j0 = blockIdx.x * 16;
    const int j  = j0 + lr;

    // ---- stage W slice into LDS in fragment-linear order (once) ----
    #pragma unroll
    for (int g = 0; g < 3; ++g)
        #pragma unroll
        for (int ks = 0; ks < 8; ++ks) {
            bf16x8 v = *(const bf16x8*)(Whh + (size_t)(g * Hd + j) * Hd
                                        + w * 256 + ks * 32 + lg * 8);
            *(bf16x8*)(Wl + ((((w * 3 + g) * 8 + ks) * 64) + l) * 8) = v;
        }

    const float bh0 = b_hh[j], bh1 = b_hh[Hd + j], bh2 = b_hh[2 * Hd + j];

    // ---- h carried in f32 regs; initial load (prev-kernel data, cached) ----
    float hp[4];
    {
        const short* hin0 = (p0 & 1) ? hb1 : hb0;
        #pragma unroll
        for (int v = 0; v < 4; ++v)
            hp[v] = bf2f(hin0[(size_t)(w * 16 + lg * 4 + v) * Hd + j]);
    }
    // ---- prefetch xp for step 0 ----
    float xr[4], xz[4], xn[4];
    #pragma unroll
    for (int v = 0; v < 4; ++v) {
        const int b = w * 16 + lg * 4 + v;
        const float* xrow = xp + (size_t)(b * xp_rs) * G3;
        xr[v] = xrow[j]; xz[v] = xrow[Hd + j]; xn[v] = xrow[2 * Hd + j];
    }
    __syncthreads();   // Wl ready

    for (int s = 0; s < T; ++s) {
        const short* hin  = ((p0 + s) & 1) ? hb1 : hb0;
        short*       hout = ((p0 + s) & 1) ? hb0 : hb1;

        // ---- wait for all blocks' step s-1 stores ----
        if (s > 0) {
            const unsigned tgt = (unsigned)s;
            unsigned f = __hip_atomic_load(&flags[l], __ATOMIC_RELAXED,
                                           __HIP_MEMORY_SCOPE_AGENT);
            while (!__all((int)(f >= tgt))) {
                __builtin_amdgcn_s_sleep(1);
                f = __hip_atomic_load(&flags[l], __ATOMIC_RELAXED,
                                      __HIP_MEMORY_SCOPE_AGENT);
            }
            asm volatile("" ::: "memory");
        }

        // ---- A-frags: relaxed atomic u64 loads (coherence-point reads) ----
        bf16x8 A[4][8];
        #pragma unroll
        for (int mt = 0; mt < 4; ++mt)
            #pragma unroll
            for (int ks = 0; ks < 8; ++ks) {
                const u64* pa = (const u64*)(hin + (size_t)(mt * 16 + lr) * Hd
                                             + w * 256 + ks * 32 + lg * 8);
                union { u64 u[2]; bf16x8 v; } t;
                t.u[0] = __hip_atomic_load(pa, __ATOMIC_RELAXED,
                                           __HIP_MEMORY_SCOPE_AGENT);
                t.u[1] = __hip_atomic_load(pa + 1, __ATOMIC_RELAXED,
                                           __HIP_MEMORY_SCOPE_AGENT);
                A[mt][ks] = t.v;
            }

        // ---- 96 MFMA: K-quarter partials, 4 m-tiles x 3 gates ----
        f32x4 acc[4][3] = {};
        #pragma unroll
        for (int ks = 0; ks < 8; ++ks) {
            bf16x8 B0 = *(const bf16x8*)(Wl + ((((w * 3 + 0) * 8 + ks) * 64) + l) * 8);
            bf16x8 B1 = *(const bf16x8*)(Wl + ((((w * 3 + 1) * 8 + ks) * 64) + l) * 8);
            bf16x8 B2 = *(const bf16x8*)(Wl + ((((w * 3 + 2) * 8 + ks) * 64) + l) * 8);
            #pragma unroll
            for (int mt = 0; mt < 4; ++mt) {
                acc[mt][0] = MFMA(A[mt][ks], B0, acc[mt][0]);
                acc[mt][1] = MFMA(A[mt][ks], B1, acc[mt][1]);
                acc[mt][2] = MFMA(A[mt][ks], B2, acc[mt][2]);
            }
        }

        // ---- cross-wave K reduction via LDS (conflict-free) ----
        #pragma unroll
        for (int mt = 0; mt < 4; ++mt)
            #pragma unroll
            for (int g = 0; g < 3; ++g)
                *(f32x4*)&xch[w][mt][g][l * 4] = acc[mt][g];
        __syncthreads();
        f32x4 tot[3];
        #pragma unroll
        for (int g = 0; g < 3; ++g) {
            f32x4 t0 = *(const f32x4*)&xch[0][w][g][l * 4];
            f32x4 t1 = *(const f32x4*)&xch[1][w][g][l * 4];
            f32x4 t2 = *(const f32x4*)&xch[2][w][g][l * 4];
            f32x4 t3 = *(const f32x4*)&xch[3][w][g][l * 4];
            tot[g] = (t0 + t1) + (t2 + t3);
        }

        // ---- gates + h update into LDS stage ----
        #pragma unroll
        for (int v = 0; v < 4; ++v) {
            const int b = w * 16 + lg * 4 + v;
            const float rg = 1.f / (1.f + __expf(-(xr[v] + tot[0][v] + bh0)));
            const float zg = 1.f / (1.f + __expf(-(xz[v] + tot[1][v] + bh1)));
            const float ng = tanhf(xn[v] + rg * (tot[2][v] + bh2));
            const float hv = (1.f - zg) * ng + zg * hp[v];
            hp[v] = hv;
            hstage[b][lr] = f2bf(hv);
        }

        // ---- prefetch next step's xp (overlaps store/flag/poll) ----
        if (s != T - 1) {
            #pragma unroll
            for (int v = 0; v < 4; ++v) {
                const int b = w * 16 + lg * 4 + v;
                const float* xrow = xp + (size_t)(b * xp_rs + (s + 1) * xp_ts) * G3;
                xr[v] = xrow[j]; xz[v] = xrow[Hd + j]; xn[v] = xrow[2 * Hd + j];
            }
        }

        __syncthreads();   // hstage complete; xch reads done

        // ---- pack + publish h (atomic, uncached) + out_seq (plain) ----
        {
            const int b = tid >> 2, part = tid & 3;
            const u64 pv = *(const u64*)&hstage[b][part * 4];
            __hip_atomic_store((u64*)(hout + (size_t)b * Hd + j0 + part * 4), pv,
                               __ATOMIC_RELAXED, __HIP_MEMORY_SCOPE_AGENT);
            if (out_seq)
                *(u64*)(out_seq + ((size_t)s * 64 + b) * Hd + j0 + part * 4) = pv;
        }

        if (s != T - 1) {
            __syncthreads();   // drains vmcnt: all 256 threads' stores acked
            if (tid == 0)
                __hip_atomic_store(&flags[blockIdx.x], (unsigned)(s + 1),
                                   __ATOMIC_RELAXED, __HIP_MEMORY_SCOPE_AGENT);
        }
    }
}

// ---------------------------------------------------------------------------
// Skinny MFMA GEMM (unchanged): C[64,N]f32 = A[64,1024]bf16 * W[N,1024]^T + b.
// ---------------------------------------------------------------------------
template<bool WF32>
__global__ __launch_bounds__(64)
void skinny_mfma(const short* __restrict__ A,
                 const void* __restrict__ Wp,
                 const float* __restrict__ bias,
                 float* __restrict__ C, int N)
{
    const int l = threadIdx.x;
    const int lr = l & 15, lg = l >> 4;
    const int n0 = blockIdx.x * 16;
    const size_t wrow = (size_t)(n0 + lr) * Hd + lg * 8;
    const short* pa = A + (size_t)lr * Hd + lg * 8;

    f32x4 acc0 = {}, acc1 = {}, acc2 = {}, acc3 = {};

    auto ldA = [&](int mtt, int ks) {
        return *(const bf16x8*)(pa + mtt * 16 * Hd + ks * 32);
    };
    auto ldW = [&](int ks) -> bf16x8 {
        if constexpr (WF32) {
            const float* p = (const float*)Wp + wrow + ks * 32;
            float4 x = *(const float4*)p;
            float4 y = *(const float4*)(p + 4);
            bf16x8 r;
            r[0]=f2bf(x.x); r[1]=f2bf(x.y); r[2]=f2bf(x.z); r[3]=f2bf(x.w);
            r[4]=f2bf(y.x); r[5]=f2bf(y.y); r[6]=f2bf(y.z); r[7]=f2bf(y.w);
            return r;
        } else {
            return *(const bf16x8*)((const short*)Wp + wrow + ks * 32);
        }
    };

    bf16x8 a00=ldA(0,0), a01=ldA(1,0), a02=ldA(2,0), a03=ldA(3,0), w0=ldW(0);
    bf16x8 a10=ldA(0,1), a11=ldA(1,1), a12=ldA(2,1), a13=ldA(3,1), w1=ldW(1);

    #pragma unroll
    for (int ks = 0; ks < 32; ks += 2) {
        const int k2 = (ks + 2) & 31;
        const int k3 = (ks + 3) & 31;
        acc0 = MFMA(a00, w0, acc0);
        acc1 = MFMA(a01, w0, acc1);
        acc2 = MFMA(a02, w0, acc2);
        acc3 = MFMA(a03, w0, acc3);
        a00=ldA(0,k2); a01=ldA(1,k2); a02=ldA(2,k2); a03=ldA(3,k2); w0=ldW(k2);
        acc0 = MFMA(a10, w1, acc0);
        acc1 = MFMA(a11, w1, acc1);
        acc2 = MFMA(a12, w1, acc2);
        acc3 = MFMA(a13, w1, acc3);
        a10=ldA(0,k3); a11=ldA(1,k3); a12=ldA(2,k3); a13=ldA(3,k3); w1=ldW(k3);
    }

    const float bn = bias[n0 + lr];
    #pragma unroll
    for (int v = 0; v < 4; ++v) {
        C[(size_t)( 0 + lg * 4 + v) * N + n0 + lr] = acc0[v] + bn;
        C[(size_t)(16 + lg * 4 + v) * N + n0 + lr] = acc1[v] + bn;
        C[(size_t)(32 + lg * 4 + v) * N + n0 + lr] = acc2[v] + bn;
        C[(size_t)(48 + lg * 4 + v) * N + n0 + lr] = acc3[v] + bn;
    }
}

// ---------------------------------------------------------------------------
// Row log-softmax over V=20000, out[b][step][v].
// ---------------------------------------------------------------------------
__global__ __launch_bounds__(256)
void log_softmax_k(const float* __restrict__ logits, float* __restrict__ out, int step)
{
    __shared__ float red[4];
    const int b   = blockIdx.x;
    const int tid = threadIdx.x;
    const float* row = logits + (size_t)b * Vv;

    float m = -1e30f;
    for (int v = tid; v < Vv; v += 256) m = fmaxf(m, row[v]);
    #pragma unroll
    for (int off = 32; off > 0; off >>= 1) m = fmaxf(m, __shfl_down(m, off, 64));
    if ((tid & 63) == 0) red[tid >> 6] = m;
    __syncthreads();
    m = fmaxf(fmaxf(red[0], red[1]), fmaxf(red[2], red[3]));
    __syncthreads();

    float s = 0.f;
    for (int v = tid; v < Vv; v += 256) s += expf(row[v] - m);
    #pragma unroll
    for (int off = 32; off > 0; off >>= 1) s += __shfl_down(s, off, 64);
    if ((tid & 63) == 0) red[tid >> 6] = s;
    __syncthreads();
    s = red[0] + red[1] + red[2] + red[3];
    const float lse = m + logf(s);

    float* orow = out + ((size_t)b * ML + step) * Vv;
    for (int v = tid; v < Vv; v += 256) orow[v] = row[v] - lse;
}

// ---------------------------------------------------------------------------
extern "C" void kernel_launch(void* const* d_in, const int* in_sizes, int n_in,
                              void* d_out, int out_size, void* d_ws, size_t ws_size,
                              hipStream_t stream)
{
    (void)in_sizes; (void)n_in; (void)out_size; (void)ws_size;
    const float* vid   = (const float*)d_in[0];
    const float* W_ih1 = (const float*)d_in[1];
    const float* W_hh1 = (const float*)d_in[2];
    const float* b_ih1 = (const float*)d_in[3];
    const float* b_hh1 = (const float*)d_in[4];
    const float* W_ih2 = (const float*)d_in[5];   // (3072,1536); cols 0..1023 used
    const float* W_hh2 = (const float*)d_in[6];
    const float* b_ih2 = (const float*)d_in[7];
    const float* b_hh2 = (const float*)d_in[8];
    const float* W_obj = (const float*)d_in[9];
    const float* b_obj = (const float*)d_in[10];
    const float* W_rel = (const float*)d_in[11];
    const float* b_rel = (const float*)d_in[12];
    float* out = (float*)d_out;

    // workspace carve-up
    char* p = (char*)d_ws;
    short* vid_bf   = (short*)p; p += (size_t)2048 * Dv * 2;        // 8.0 MB
    short* Wih1_bf  = (short*)p; p += (size_t)G3 * Dv * 2;          // 12.6 MB
    short* Whh1_bf  = (short*)p; p += (size_t)G3 * Hd * 2;          // 6.3 MB
    short* Wih2c_bf = (short*)p; p += (size_t)G3 * Hd * 2;          // 6.3 MB
    short* Whh2_bf  = (short*)p; p += (size_t)G3 * Hd * 2;          // 6.3 MB
    short* out1_bf  = (short*)p; p += (size_t)2048 * Hd * 2;        // 4.2 MB
    // --- zero zone (one memset): h double-buffers + flag arrays ---
    char* zz = p;
    short* h1a = (short*)p; p += (size_t)64 * Hd * 2;
    short* h1b = (short*)p; p += (size_t)64 * Hd * 2;
    short* h2a = (short*)p; p += (size_t)64 * Hd * 2;
    short* h2b = (short*)p; p += (size_t)64 * Hd * 2;
    unsigned int* bar = (unsigned int*)p; p += 4096;                // 2 sets x 512 uints
    size_t zz_bytes = (size_t)(p - zz);
    float* xp1    = (float*)p; p += (size_t)2048 * G3 * 4;          // 25.2 MB (also xp2)
    float* xp2t   = (float*)p; p += (size_t)64 * G3 * 4;
    float* logits = (float*)p; p += (size_t)64 * Vv * 4;

    hipMemsetAsync(zz, 0, zz_bytes, stream);

    // conversions to bf16
    {
        long t8;
        t8 = (long)2048 * Dv / 8;
        cvt_f32_bf16<<<(t8 + 255) / 256, 256, 0, stream>>>(vid, vid_bf, t8, t8, 0, 0);
        t8 = (long)G3 * Dv / 8;
        cvt_f32_bf16<<<(t8 + 255) / 256, 256, 0, stream>>>(W_ih1, Wih1_bf, t8, t8, 0, 0);
        t8 = (long)G3 * Hd / 8;
        cvt_f32_bf16<<<(t8 + 255) / 256, 256, 0, stream>>>(W_hh1, Whh1_bf, t8, t8, 0, 0);
        cvt_f32_bf16<<<(t8 + 255) / 256, 256, 0, stream>>>(W_hh2, Whh2_bf, t8, t8, 0, 0);
        cvt_f32_bf16<<<(t8 + 255) / 256, 256, 0, stream>>>(W_ih2, Wih2c_bf, t8, Hd / 8,
                                                           Hd + 512, Hd);
    }

    // Phase 1: xp1 = vid @ W_ih1^T + b_ih1   (M=2048, N=3072, K=2048)
    gemm_mfma_128<<<dim3(G3 / 128, 2048 / 128), 256, 0, stream>>>(
        vid_bf, Dv, Wih1_bf, Dv, b_ih1, xp1, G3, Dv);

    // Phase 2: layer-1 scan, ONE launch (xp row = b*32 + s), writes out1
    gru_scan<<<64, 256, 0, stream>>>(xp1, Tt, 1, Whh1_bf, b_hh1,
                                     h1a, h1b, 0, out1_bf, Tt, bar + 0);
    int p1 = 0;  // (0 + 32) & 1 == 0 -> final h1 in h1a

    // Phase 3: xp2 = out1 @ W_ih2[:, :H]^T + b_ih2  (M=2048, N=3072, K=1024)
    float* xp2 = xp1;
    gemm_mfma_128<<<dim3(G3 / 128, 2048 / 128), 256, 0, stream>>>(
        out1_bf, Hd, Wih2c_bf, Hd, b_ih2, xp2, G3, Hd);

    // Phase 4: layer-2 scan, ONE launch (xp row = s*64 + b)
    gru_scan<<<64, 256, 0, stream>>>(xp2, 1, 64, Whh2_bf, b_hh2,
                                     h2a, h2b, 0, nullptr, Tt, bar + 512);
    int p2 = 0;

    // Phase 5: decode (gru_scan with T=1; flag/poll paths never execute)
    for (int i = 0; i < ML; ++i) {
        gru_scan<<<64, 256, 0, stream>>>(b_ih1, 0, 0, Whh1_bf, b_hh1,
                                         h1a, h1b, p1, nullptr, 1, bar);
        p1 ^= 1;
        short* h1cur = p1 ? h1b : h1a;
        skinny_mfma<false><<<G3 / 16, 64, 0, stream>>>(h1cur, (const void*)Wih2c_bf,
                                                       b_ih2, xp2t, G3);
        gru_scan<<<64, 256, 0, stream>>>(xp2t, 1, 0, Whh2_bf, b_hh2,
                                         h2a, h2b, p2, nullptr, 1, bar);
        p2 ^= 1;
        short* h2cur = p2 ? h2b : h2a;
        const float* Wo = (i == 1) ? W_rel : W_obj;
        const float* bo = (i == 1) ? b_rel : b_obj;
        skinny_mfma<true><<<Vv / 16, 64, 0, stream>>>(h2cur, (const void*)Wo, bo,
                                                      logits, Vv);
        log_softmax_k<<<64, 256, 0, stream>>>(logits, out, i);
    }
}

// Round 7
// 679.446 us; speedup vs baseline: 1.6800x; 1.6800x over previous
//
#include <hip/hip_runtime.h>
#include <math.h>

#define Bsz 64
#define Tt  32
#define Dv  2048
#define Hd  1024
#define G3  3072
#define Vv  20000
#define ML  3

typedef __attribute__((ext_vector_type(8))) short bf16x8;
typedef __attribute__((ext_vector_type(4))) float f32x4;
typedef unsigned long long u64;
#define MFMA(a,b,c) __builtin_amdgcn_mfma_f32_16x16x32_bf16(a,b,c,0,0,0)

__device__ __forceinline__ short f2bf(float f) {
    union { float f; unsigned u; } v; v.f = f;
    unsigned r = v.u + 0x7fffu + ((v.u >> 16) & 1u);
    return (short)(r >> 16);
}
__device__ __forceinline__ float bf2f(short s) {
    union { unsigned u; float f; } v; v.u = ((unsigned)(unsigned short)s) << 16;
    return v.f;
}

// One wave (64 lanes) polls 64 per-block flags until all >= tgt.
__device__ __forceinline__ void poll_flags(const unsigned* fl, unsigned tgt) {
    const int lane = threadIdx.x & 63;
    unsigned f = __hip_atomic_load(&fl[lane], __ATOMIC_RELAXED,
                                   __HIP_MEMORY_SCOPE_AGENT);
    while (!__all((int)(f >= tgt))) {
        __builtin_amdgcn_s_sleep(2);
        f = __hip_atomic_load(&fl[lane], __ATOMIC_RELAXED,
                              __HIP_MEMORY_SCOPE_AGENT);
    }
}

// ---------------------------------------------------------------------------
// fp32 -> bf16 conversion, 8 elems/thread, optional row slicing (for W_ih2).
// ---------------------------------------------------------------------------
__global__ __launch_bounds__(256)
void cvt_f32_bf16(const float* __restrict__ src, short* __restrict__ dst,
                  long total8, long cols8, int src_ld, int dst_ld)
{
    long i = (long)blockIdx.x * 256 + threadIdx.x;
    if (i >= total8) return;
    long r = i / cols8; long c = i - r * cols8;
    const float* s = src + r * (long)src_ld + c * 8;
    float4 x = *(const float4*)s;
    float4 y = *(const float4*)(s + 4);
    bf16x8 o;
    o[0]=f2bf(x.x); o[1]=f2bf(x.y); o[2]=f2bf(x.z); o[3]=f2bf(x.w);
    o[4]=f2bf(y.x); o[5]=f2bf(y.y); o[6]=f2bf(y.z); o[7]=f2bf(y.w);
    *(bf16x8*)(dst + r * (long)dst_ld + c * 8) = o;
}

// ---------------------------------------------------------------------------
// Big MFMA GEMM (unchanged): C[M,N] = A*W^T + bias, 128x128 tile.
// ---------------------------------------------------------------------------
__global__ __launch_bounds__(256)
void gemm_mfma_128(const short* __restrict__ A, int lda,
                   const short* __restrict__ W, int ldw,
                   const float* __restrict__ bias,
                   float* __restrict__ C, int ldc, int K)
{
    __shared__ __align__(16) short As[128 * 40];
    __shared__ __align__(16) short Bs[128 * 40];
    const int tid = threadIdx.x;
    const int w = tid >> 6, l = tid & 63;
    const int wm = w >> 1, wn = w & 1;
    const int lr = l & 15, lg = l >> 4;
    const int m0 = blockIdx.y * 128, n0 = blockIdx.x * 128;
    const int sm = tid >> 2;
    const int skg = tid & 3;

    f32x4 acc[4][4] = {};

    for (int k0 = 0; k0 < K; k0 += 32) {
        #pragma unroll
        for (int i = 0; i < 2; ++i) {
            const int m = i * 64 + sm;
            bf16x8 av = *(const bf16x8*)(A + (size_t)(m0 + m) * lda + k0 + skg * 8);
            bf16x8 wv = *(const bf16x8*)(W + (size_t)(n0 + m) * ldw + k0 + skg * 8);
            *(bf16x8*)(As + m * 40 + skg * 8) = av;
            *(bf16x8*)(Bs + m * 40 + skg * 8) = wv;
        }
        __syncthreads();
        bf16x8 af[4], bfr[4];
        #pragma unroll
        for (int mt = 0; mt < 4; ++mt) {
            const int m = wm * 64 + mt * 16 + lr;
            const int n = wn * 64 + mt * 16 + lr;
            af[mt]  = *(const bf16x8*)(As + m * 40 + lg * 8);
            bfr[mt] = *(const bf16x8*)(Bs + n * 40 + lg * 8);
        }
        #pragma unroll
        for (int mt = 0; mt < 4; ++mt)
            #pragma unroll
            for (int nt = 0; nt < 4; ++nt)
                acc[mt][nt] = MFMA(af[mt], bfr[nt], acc[mt][nt]);
        __syncthreads();
    }

    #pragma unroll
    for (int mt = 0; mt < 4; ++mt)
        #pragma unroll
        for (int nt = 0; nt < 4; ++nt)
            #pragma unroll
            for (int v = 0; v < 4; ++v) {
                const int m = m0 + wm * 64 + mt * 16 + lg * 4 + v;
                const int n = n0 + wn * 64 + nt * 16 + lr;
                C[(size_t)m * ldc + n] = acc[mt][nt][v] + bias[n];
            }
}

// ---------------------------------------------------------------------------
// Fused encoder pipeline: 192 blocks = 3 groups of 64.
//   role 0 (G1): layer-1 GRU step t; reads out1h[t], writes out1h[t+1].
//   role 1 (GP): xp2[t] = out1[t] @ W_ih2c^T + b_ih2; reads out1h[t+1],
//                writes xp2s[t] (fp32, atomic u32).
//   role 2 (G2): layer-2 GRU step t; reads xp2s[t] + h2h[t], writes h2h[t+1].
// Steady-state: the three groups run CONCURRENTLY, one step apart.
// History buffers (slot per t) => consumers use plain first-touch loads
// (launch-time L2 inv + write-through atomic stores + post-flag reads =>
// never stale); producers publish via relaxed agent-scope atomics; flags are
// per-block step counters (no fences anywhere, L2 never invalidated).
// W slice (48 rows x 1024) per block staged once in LDS, fragment-linear.
// ---------------------------------------------------------------------------
__global__ __launch_bounds__(256, 1)
void enc_pipeline(const float* __restrict__ xp1,
                  const short* __restrict__ Whh1, const float* __restrict__ b_hh1,
                  const short* __restrict__ Wih2, const float* __restrict__ b_ih2,
                  const short* __restrict__ Whh2, const float* __restrict__ b_hh2,
                  short* __restrict__ out1h,   // (33,64,1024) bf16, slot0 = 0
                  float* __restrict__ xp2s,    // (32,64,3072) fp32
                  short* __restrict__ h2h,     // (33,64,1024) bf16, slot0 = 0
                  short* __restrict__ h1fin, short* __restrict__ h2fin,
                  unsigned* __restrict__ flags1, unsigned* __restrict__ flagsP,
                  unsigned* __restrict__ flags2)
{
    __shared__ __align__(16) short Wl[4 * 3 * 8 * 64 * 8];   // 98304 B
    __shared__ __align__(16) float xch[4][4][3][256];        // 49152 B
    __shared__ __align__(16) short hstage[64][16];           // 2048 B
    const int tid = threadIdx.x;
    const int w  = tid >> 6;
    const int l  = tid & 63;
    const int lr = l & 15, lg = l >> 4;
    const int role = blockIdx.x >> 6;         // 0=G1, 1=GP, 2=G2
    const int k    = blockIdx.x & 63;
    const int j0 = k * 16;
    const int j  = j0 + lr;

    const short* Wsrc = (role == 0) ? Whh1 : (role == 1) ? Wih2 : Whh2;
    const float* bias = (role == 0) ? b_hh1 : (role == 1) ? b_ih2 : b_hh2;

    // ---- stage W slice into LDS, fragment-linear (once) ----
    #pragma unroll
    for (int g = 0; g < 3; ++g)
        #pragma unroll
        for (int ks = 0; ks < 8; ++ks) {
            bf16x8 v = *(const bf16x8*)(Wsrc + (size_t)(g * Hd + j) * Hd
                                        + w * 256 + ks * 32 + lg * 8);
            *(bf16x8*)(Wl + ((((w * 3 + g) * 8 + ks) * 64) + l) * 8) = v;
        }

    const float b0 = bias[j], b1 = bias[Hd + j], b2 = bias[2 * Hd + j];
    short* Ab = (role == 2) ? h2h : out1h;
    short* hfin = (role == 0) ? h1fin : h2fin;

    float hp[4] = {0.f, 0.f, 0.f, 0.f};     // h carry (GRU roles); h(-1)=0
    float xr[4], xz[4], xn[4];
    if (role == 0) {                         // prefetch xp1 for t=0
        #pragma unroll
        for (int v = 0; v < 4; ++v) {
            const int b = w * 16 + lg * 4 + v;
            const float* xrow = xp1 + (size_t)(b * Tt) * G3;
            xr[v] = xrow[j]; xz[v] = xrow[Hd + j]; xn[v] = xrow[2 * Hd + j];
        }
    }
    __syncthreads();   // Wl ready

    for (int t = 0; t < Tt; ++t) {
        // ---- producer waits (wave-specialized polling) ----
        if (role == 0)      { if (w == 0) poll_flags(flags1, (unsigned)t); }
        else if (role == 1) { if (w == 0) poll_flags(flags1, (unsigned)(t + 1)); }
        else {
            if (w == 0)      poll_flags(flagsP, (unsigned)(t + 1));
            else if (w == 1) poll_flags(flags2, (unsigned)t);
        }
        __syncthreads();
        asm volatile("" ::: "memory");

        // ---- A-frags: plain loads from history slot (first-touch fresh) ----
        const short* hin = Ab + (size_t)(role == 1 ? t + 1 : t) * (64 * Hd);
        bf16x8 A[4][8];
        #pragma unroll
        for (int mt = 0; mt < 4; ++mt)
            #pragma unroll
            for (int ks = 0; ks < 8; ++ks)
                A[mt][ks] = *(const bf16x8*)(hin + (size_t)(mt * 16 + lr) * Hd
                                             + w * 256 + ks * 32 + lg * 8);
        if (role == 2) {   // xp2 for this step (produced by GP, post-flag)
            #pragma unroll
            for (int v = 0; v < 4; ++v) {
                const int b = w * 16 + lg * 4 + v;
                const float* xrow = xp2s + ((size_t)t * 64 + b) * G3;
                xr[v] = xrow[j]; xz[v] = xrow[Hd + j]; xn[v] = xrow[2 * Hd + j];
            }
        }

        // ---- 96 MFMA: K-quarter partials, 4 m-tiles x 3 gates ----
        f32x4 acc[4][3] = {};
        #pragma unroll
        for (int ks = 0; ks < 8; ++ks) {
            bf16x8 B0 = *(const bf16x8*)(Wl + ((((w * 3 + 0) * 8 + ks) * 64) + l) * 8);
            bf16x8 B1 = *(const bf16x8*)(Wl + ((((w * 3 + 1) * 8 + ks) * 64) + l) * 8);
            bf16x8 B2 = *(const bf16x8*)(Wl + ((((w * 3 + 2) * 8 + ks) * 64) + l) * 8);
            #pragma unroll
            for (int mt = 0; mt < 4; ++mt) {
                acc[mt][0] = MFMA(A[mt][ks], B0, acc[mt][0]);
                acc[mt][1] = MFMA(A[mt][ks], B1, acc[mt][1]);
                acc[mt][2] = MFMA(A[mt][ks], B2, acc[mt][2]);
            }
        }

        // ---- cross-wave K reduction via LDS ----
        #pragma unroll
        for (int mt = 0; mt < 4; ++mt)
            #pragma unroll
            for (int g = 0; g < 3; ++g)
                *(f32x4*)&xch[w][mt][g][l * 4] = acc[mt][g];
        __syncthreads();
        f32x4 tot[3];
        #pragma unroll
        for (int g = 0; g < 3; ++g) {
            f32x4 t0 = *(const f32x4*)&xch[0][w][g][l * 4];
            f32x4 t1 = *(const f32x4*)&xch[1][w][g][l * 4];
            f32x4 t2 = *(const f32x4*)&xch[2][w][g][l * 4];
            f32x4 t3 = *(const f32x4*)&xch[3][w][g][l * 4];
            tot[g] = (t0 + t1) + (t2 + t3);
        }

        if (role == 1) {
            // ---- GP: xp2s[t][b][g*1024+j] = tot + bias (atomic u32) ----
            const float bg[3] = {b0, b1, b2};
            #pragma unroll
            for (int v = 0; v < 4; ++v) {
                const int b = w * 16 + lg * 4 + v;
                #pragma unroll
                for (int g = 0; g < 3; ++g) {
                    union { float f; unsigned u; } cv;
                    cv.f = tot[g][v] + bg[g];
                    __hip_atomic_store(
                        (unsigned*)(xp2s + ((size_t)t * 64 + b) * G3 + g * Hd + j),
                        cv.u, __ATOMIC_RELAXED, __HIP_MEMORY_SCOPE_AGENT);
                }
            }
            __syncthreads();   // drains vmcnt: stores acked at coherence point
        } else {
            // ---- GRU gates + h update into LDS stage ----
            #pragma unroll
            for (int v = 0; v < 4; ++v) {
                const int b = w * 16 + lg * 4 + v;
                const float rg = 1.f / (1.f + __expf(-(xr[v] + tot[0][v] + b0)));
                const float zg = 1.f / (1.f + __expf(-(xz[v] + tot[1][v] + b1)));
                const float ng = tanhf(xn[v] + rg * (tot[2][v] + b2));
                const float hv = (1.f - zg) * ng + zg * hp[v];
                hp[v] = hv;
                hstage[b][lr] = f2bf(hv);
            }
            if (role == 0 && t != Tt - 1) {   // prefetch next xp1
                #pragma unroll
                for (int v = 0; v < 4; ++v) {
                    const int b = w * 16 + lg * 4 + v;
                    const float* xrow = xp1 + (size_t)(b * Tt + t + 1) * G3;
                    xr[v] = xrow[j]; xz[v] = xrow[Hd + j]; xn[v] = xrow[2 * Hd + j];
                }
            }
            __syncthreads();   // hstage complete; xch WAR safe

            // ---- publish h slot t+1 (atomic u64, write-through) ----
            {
                const int b = tid >> 2, part = tid & 3;
                const u64 pv = *(const u64*)&hstage[b][part * 4];
                __hip_atomic_store(
                    (u64*)(Ab + (size_t)(t + 1) * (64 * Hd) + b * Hd + j0 + part * 4),
                    pv, __ATOMIC_RELAXED, __HIP_MEMORY_SCOPE_AGENT);
                if (t == Tt - 1)   // final state for the decode phase
                    *(u64*)(hfin + (size_t)b * Hd + j0 + part * 4) = pv;
            }
            __syncthreads();   // drains vmcnt: publishes acked
        }

        if (tid == 0) {
            unsigned* fl = (role == 0) ? flags1 : (role == 1) ? flagsP : flags2;
            __hip_atomic_store(&fl[k], (unsigned)(t + 1),
                               __ATOMIC_RELAXED, __HIP_MEMORY_SCOPE_AGENT);
        }
    }
}

// ---------------------------------------------------------------------------
// Decode GRU step (r6's gru_scan, used with T=1 only; flag paths inert).
// ---------------------------------------------------------------------------
__global__ __launch_bounds__(256, 1)
void gru_scan(const float* __restrict__ xp, int xp_rs, int xp_ts,
              const short* __restrict__ Whh,
              const float* __restrict__ b_hh,
              short* __restrict__ hb0, short* __restrict__ hb1, int p0,
              short* __restrict__ out_seq,
              int T, unsigned int* __restrict__ flags)
{
    __shared__ __align__(16) short Wl[4 * 3 * 8 * 64 * 8];
    __shared__ __align__(16) float xch[4][4][3][256];
    __shared__ __align__(16) short hstage[64][16];
    const int tid = threadIdx.x;
    const int w  = tid >> 6;
    const int l  = tid & 63;
    const int lr = l & 15, lg = l >> 4;
    const int j0 = blockIdx.x * 16;
    const int j  = j0 + lr;

    #pragma unroll
    for (int g = 0; g < 3; ++g)
        #pragma unroll
        for (int ks = 0; ks < 8; ++ks) {
            bf16x8 v = *(const bf16x8*)(Whh + (size_t)(g * Hd + j) * Hd
                                        + w * 256 + ks * 32 + lg * 8);
            *(bf16x8*)(Wl + ((((w * 3 + g) * 8 + ks) * 64) + l) * 8) = v;
        }

    const float bh0 = b_hh[j], bh1 = b_hh[Hd + j], bh2 = b_hh[2 * Hd + j];

    float hp[4];
    {
        const short* hin0 = (p0 & 1) ? hb1 : hb0;
        #pragma unroll
        for (int v = 0; v < 4; ++v)
            hp[v] = bf2f(hin0[(size_t)(w * 16 + lg * 4 + v) * Hd + j]);
    }
    float xr[4], xz[4], xn[4];
    #pragma unroll
    for (int v = 0; v < 4; ++v) {
        const int b = w * 16 + lg * 4 + v;
        const float* xrow = xp + (size_t)(b * xp_rs) * G3;
        xr[v] = xrow[j]; xz[v] = xrow[Hd + j]; xn[v] = xrow[2 * Hd + j];
    }
    __syncthreads();

    for (int s = 0; s < T; ++s) {
        const short* hin  = ((p0 + s) & 1) ? hb1 : hb0;
        short*       hout = ((p0 + s) & 1) ? hb0 : hb1;

        if (s > 0) {
            const unsigned tgt = (unsigned)s;
            unsigned f = __hip_atomic_load(&flags[l], __ATOMIC_RELAXED,
                                           __HIP_MEMORY_SCOPE_AGENT);
            while (!__all((int)(f >= tgt))) {
                __builtin_amdgcn_s_sleep(1);
                f = __hip_atomic_load(&flags[l], __ATOMIC_RELAXED,
                                      __HIP_MEMORY_SCOPE_AGENT);
            }
            asm volatile("" ::: "memory");
        }

        bf16x8 A[4][8];
        #pragma unroll
        for (int mt = 0; mt < 4; ++mt)
            #pragma unroll
            for (int ks = 0; ks < 8; ++ks) {
                const u64* pa = (const u64*)(hin + (size_t)(mt * 16 + lr) * Hd
                                             + w * 256 + ks * 32 + lg * 8);
                union { u64 u[2]; bf16x8 v; } t;
                t.u[0] = __hip_atomic_load(pa, __ATOMIC_RELAXED,
                                           __HIP_MEMORY_SCOPE_AGENT);
                t.u[1] = __hip_atomic_load(pa + 1, __ATOMIC_RELAXED,
                                           __HIP_MEMORY_SCOPE_AGENT);
                A[mt][ks] = t.v;
            }

        f32x4 acc[4][3] = {};
        #pragma unroll
        for (int ks = 0; ks < 8; ++ks) {
            bf16x8 B0 = *(const bf16x8*)(Wl + ((((w * 3 + 0) * 8 + ks) * 64) + l) * 8);
            bf16x8 B1 = *(const bf16x8*)(Wl + ((((w * 3 + 1) * 8 + ks) * 64) + l) * 8);
            bf16x8 B2 = *(const bf16x8*)(Wl + ((((w * 3 + 2) * 8 + ks) * 64) + l) * 8);
            #pragma unroll
            for (int mt = 0; mt < 4; ++mt) {
                acc[mt][0] = MFMA(A[mt][ks], B0, acc[mt][0]);
                acc[mt][1] = MFMA(A[mt][ks], B1, acc[mt][1]);
                acc[mt][2] = MFMA(A[mt][ks], B2, acc[mt][2]);
            }
        }

        #pragma unroll
        for (int mt = 0; mt < 4; ++mt)
            #pragma unroll
            for (int g = 0; g < 3; ++g)
                *(f32x4*)&xch[w][mt][g][l * 4] = acc[mt][g];
        __syncthreads();
        f32x4 tot[3];
        #pragma unroll
        for (int g = 0; g < 3; ++g) {
            f32x4 t0 = *(const f32x4*)&xch[0][w][g][l * 4];
            f32x4 t1 = *(const f32x4*)&xch[1][w][g][l * 4];
            f32x4 t2 = *(const f32x4*)&xch[2][w][g][l * 4];
            f32x4 t3 = *(const f32x4*)&xch[3][w][g][l * 4];
            tot[g] = (t0 + t1) + (t2 + t3);
        }

        #pragma unroll
        for (int v = 0; v < 4; ++v) {
            const int b = w * 16 + lg * 4 + v;
            const float rg = 1.f / (1.f + __expf(-(xr[v] + tot[0][v] + bh0)));
            const float zg = 1.f / (1.f + __expf(-(xz[v] + tot[1][v] + bh1)));
            const float ng = tanhf(xn[v] + rg * (tot[2][v] + bh2));
            const float hv = (1.f - zg) * ng + zg * hp[v];
            hp[v] = hv;
            hstage[b][lr] = f2bf(hv);
        }

        if (s != T - 1) {
            #pragma unroll
            for (int v = 0; v < 4; ++v) {
                const int b = w * 16 + lg * 4 + v;
                const float* xrow = xp + (size_t)(b * xp_rs + (s + 1) * xp_ts) * G3;
                xr[v] = xrow[j]; xz[v] = xrow[Hd + j]; xn[v] = xrow[2 * Hd + j];
            }
        }
        __syncthreads();

        {
            const int b = tid >> 2, part = tid & 3;
            const u64 pv = *(const u64*)&hstage[b][part * 4];
            __hip_atomic_store((u64*)(hout + (size_t)b * Hd + j0 + part * 4), pv,
                               __ATOMIC_RELAXED, __HIP_MEMORY_SCOPE_AGENT);
            if (out_seq)
                *(u64*)(out_seq + ((size_t)s * 64 + b) * Hd + j0 + part * 4) = pv;
        }

        if (s != T - 1) {
            __syncthreads();
            if (tid == 0)
                __hip_atomic_store(&flags[blockIdx.x], (unsigned)(s + 1),
                                   __ATOMIC_RELAXED, __HIP_MEMORY_SCOPE_AGENT);
        }
    }
}

// ---------------------------------------------------------------------------
// Skinny MFMA GEMM (unchanged): C[64,N]f32 = A[64,1024]bf16 * W[N,1024]^T + b.
// ---------------------------------------------------------------------------
template<bool WF32>
__global__ __launch_bounds__(64)
void skinny_mfma(const short* __restrict__ A,
                 const void* __restrict__ Wp,
                 const float* __restrict__ bias,
                 float* __restrict__ C, int N)
{
    const int l = threadIdx.x;
    const int lr = l & 15, lg = l >> 4;
    const int n0 = blockIdx.x * 16;
    const size_t wrow = (size_t)(n0 + lr) * Hd + lg * 8;
    const short* pa = A + (size_t)lr * Hd + lg * 8;

    f32x4 acc0 = {}, acc1 = {}, acc2 = {}, acc3 = {};

    auto ldA = [&](int mtt, int ks) {
        return *(const bf16x8*)(pa + mtt * 16 * Hd + ks * 32);
    };
    auto ldW = [&](int ks) -> bf16x8 {
        if constexpr (WF32) {
            const float* p = (const float*)Wp + wrow + ks * 32;
            float4 x = *(const float4*)p;
            float4 y = *(const float4*)(p + 4);
            bf16x8 r;
            r[0]=f2bf(x.x); r[1]=f2bf(x.y); r[2]=f2bf(x.z); r[3]=f2bf(x.w);
            r[4]=f2bf(y.x); r[5]=f2bf(y.y); r[6]=f2bf(y.z); r[7]=f2bf(y.w);
            return r;
        } else {
            return *(const bf16x8*)((const short*)Wp + wrow + ks * 32);
        }
    };

    bf16x8 a00=ldA(0,0), a01=ldA(1,0), a02=ldA(2,0), a03=ldA(3,0), w0=ldW(0);
    bf16x8 a10=ldA(0,1), a11=ldA(1,1), a12=ldA(2,1), a13=ldA(3,1), w1=ldW(1);

    #pragma unroll
    for (int ks = 0; ks < 32; ks += 2) {
        const int k2 = (ks + 2) & 31;
        const int k3 = (ks + 3) & 31;
        acc0 = MFMA(a00, w0, acc0);
        acc1 = MFMA(a01, w0, acc1);
        acc2 = MFMA(a02, w0, acc2);
        acc3 = MFMA(a03, w0, acc3);
        a00=ldA(0,k2); a01=ldA(1,k2); a02=ldA(2,k2); a03=ldA(3,k2); w0=ldW(k2);
        acc0 = MFMA(a10, w1, acc0);
        acc1 = MFMA(a11, w1, acc1);
        acc2 = MFMA(a12, w1, acc2);
        acc3 = MFMA(a13, w1, acc3);
        a10=ldA(0,k3); a11=ldA(1,k3); a12=ldA(2,k3); a13=ldA(3,k3); w1=ldW(k3);
    }

    const float bn = bias[n0 + lr];
    #pragma unroll
    for (int v = 0; v < 4; ++v) {
        C[(size_t)( 0 + lg * 4 + v) * N + n0 + lr] = acc0[v] + bn;
        C[(size_t)(16 + lg * 4 + v) * N + n0 + lr] = acc1[v] + bn;
        C[(size_t)(32 + lg * 4 + v) * N + n0 + lr] = acc2[v] + bn;
        C[(size_t)(48 + lg * 4 + v) * N + n0 + lr] = acc3[v] + bn;
    }
}

// ---------------------------------------------------------------------------
// Row log-softmax over V=20000, out[b][step][v].
// ---------------------------------------------------------------------------
__global__ __launch_bounds__(256)
void log_softmax_k(const float* __restrict__ logits, float* __restrict__ out, int step)
{
    __shared__ float red[4];
    const int b   = blockIdx.x;
    const int tid = threadIdx.x;
    const float* row = logits + (size_t)b * Vv;

    float m = -1e30f;
    for (int v = tid; v < Vv; v += 256) m = fmaxf(m, row[v]);
    #pragma unroll
    for (int off = 32; off > 0; off >>= 1) m = fmaxf(m, __shfl_down(m, off, 64));
    if ((tid & 63) == 0) red[tid >> 6] = m;
    __syncthreads();
    m = fmaxf(fmaxf(red[0], red[1]), fmaxf(red[2], red[3]));
    __syncthreads();

    float s = 0.f;
    for (int v = tid; v < Vv; v += 256) s += expf(row[v] - m);
    #pragma unroll
    for (int off = 32; off > 0; off >>= 1) s += __shfl_down(s, off, 64);
    if ((tid & 63) == 0) red[tid >> 6] = s;
    __syncthreads();
    s = red[0] + red[1] + red[2] + red[3];
    const float lse = m + logf(s);

    float* orow = out + ((size_t)b * ML + step) * Vv;
    for (int v = tid; v < Vv; v += 256) orow[v] = row[v] - lse;
}

// ---------------------------------------------------------------------------
extern "C" void kernel_launch(void* const* d_in, const int* in_sizes, int n_in,
                              void* d_out, int out_size, void* d_ws, size_t ws_size,
                              hipStream_t stream)
{
    (void)in_sizes; (void)n_in; (void)out_size; (void)ws_size;
    const float* vid   = (const float*)d_in[0];
    const float* W_ih1 = (const float*)d_in[1];
    const float* W_hh1 = (const float*)d_in[2];
    const float* b_ih1 = (const float*)d_in[3];
    const float* b_hh1 = (const float*)d_in[4];
    const float* W_ih2 = (const float*)d_in[5];   // (3072,1536); cols 0..1023 used
    const float* W_hh2 = (const float*)d_in[6];
    const float* b_ih2 = (const float*)d_in[7];
    const float* b_hh2 = (const float*)d_in[8];
    const float* W_obj = (const float*)d_in[9];
    const float* b_obj = (const float*)d_in[10];
    const float* W_rel = (const float*)d_in[11];
    const float* b_rel = (const float*)d_in[12];
    float* out = (float*)d_out;

    // workspace carve-up (~105 MB)
    char* p = (char*)d_ws;
    short* vid_bf   = (short*)p; p += (size_t)2048 * Dv * 2;        // 8.0 MB
    short* Wih1_bf  = (short*)p; p += (size_t)G3 * Dv * 2;          // 12.6 MB
    short* Whh1_bf  = (short*)p; p += (size_t)G3 * Hd * 2;          // 6.3 MB
    short* Wih2c_bf = (short*)p; p += (size_t)G3 * Hd * 2;          // 6.3 MB
    short* Whh2_bf  = (short*)p; p += (size_t)G3 * Hd * 2;          // 6.3 MB
    // --- zero zone (one memset): decode h buffers + flag arrays ---
    char* zz = p;
    short* h1a = (short*)p; p += (size_t)64 * Hd * 2;
    short* h1b = (short*)p; p += (size_t)64 * Hd * 2;
    short* h2a = (short*)p; p += (size_t)64 * Hd * 2;
    short* h2b = (short*)p; p += (size_t)64 * Hd * 2;
    unsigned int* bar = (unsigned int*)p; p += 4096;   // flags1/P/2 + decode scratch
    size_t zz_bytes = (size_t)(p - zz);
    short* out1h  = (short*)p; p += (size_t)33 * 64 * Hd * 2;       // 4.3 MB
    short* h2h    = (short*)p; p += (size_t)33 * 64 * Hd * 2;       // 4.3 MB
    float* xp1    = (float*)p; p += (size_t)2048 * G3 * 4;          // 25.2 MB
    float* xp2s   = (float*)p; p += (size_t)32 * 64 * G3 * 4;       // 25.2 MB
    float* xp2t   = (float*)p; p += (size_t)64 * G3 * 4;
    float* logits = (float*)p; p += (size_t)64 * Vv * 4;

    unsigned* flags1 = bar;
    unsigned* flagsP = bar + 64;
    unsigned* flags2 = bar + 128;
    unsigned* dbar   = bar + 256;   // decode gru_scan scratch (inert at T=1)

    hipMemsetAsync(zz, 0, zz_bytes, stream);
    hipMemsetAsync(out1h, 0, (size_t)64 * Hd * 2, stream);   // slot 0 = h1(-1)=0
    hipMemsetAsync(h2h,   0, (size_t)64 * Hd * 2, stream);   // slot 0 = h2(-1)=0

    // conversions to bf16
    {
        long t8;
        t8 = (long)2048 * Dv / 8;
        cvt_f32_bf16<<<(t8 + 255) / 256, 256, 0, stream>>>(vid, vid_bf, t8, t8, 0, 0);
        t8 = (long)G3 * Dv / 8;
        cvt_f32_bf16<<<(t8 + 255) / 256, 256, 0, stream>>>(W_ih1, Wih1_bf, t8, t8, 0, 0);
        t8 = (long)G3 * Hd / 8;
        cvt_f32_bf16<<<(t8 + 255) / 256, 256, 0, stream>>>(W_hh1, Whh1_bf, t8, t8, 0, 0);
        cvt_f32_bf16<<<(t8 + 255) / 256, 256, 0, stream>>>(W_hh2, Whh2_bf, t8, t8, 0, 0);
        cvt_f32_bf16<<<(t8 + 255) / 256, 256, 0, stream>>>(W_ih2, Wih2c_bf, t8, Hd / 8,
                                                           Hd + 512, Hd);
    }

    // Phase 1: xp1 = vid @ W_ih1^T + b_ih1   (M=2048, N=3072, K=2048)
    gemm_mfma_128<<<dim3(G3 / 128, 2048 / 128), 256, 0, stream>>>(
        vid_bf, Dv, Wih1_bf, Dv, b_ih1, xp1, G3, Dv);

    // Phase 2-4 fused: layer-1 scan || projection || layer-2 scan
    enc_pipeline<<<192, 256, 0, stream>>>(
        xp1, Whh1_bf, b_hh1, Wih2c_bf, b_ih2, Whh2_bf, b_hh2,
        out1h, xp2s, h2h, h1a, h2a, flags1, flagsP, flags2);

    // Phase 5: decode (final h1 in h1a, final h2 in h2a; p1=p2=0)
    int p1 = 0, p2 = 0;
    for (int i = 0; i < ML; ++i) {
        gru_scan<<<64, 256, 0, stream>>>(b_ih1, 0, 0, Whh1_bf, b_hh1,
                                         h1a, h1b, p1, nullptr, 1, dbar);
        p1 ^= 1;
        short* h1cur = p1 ? h1b : h1a;
        skinny_mfma<false><<<G3 / 16, 64, 0, stream>>>(h1cur, (const void*)Wih2c_bf,
                                                       b_ih2, xp2t, G3);
        gru_scan<<<64, 256, 0, stream>>>(xp2t, 1, 0, Whh2_bf, b_hh2,
                                         h2a, h2b, p2, nullptr, 1, dbar);
        p2 ^= 1;
        short* h2cur = p2 ? h2b : h2a;
        const float* Wo = (i == 1) ? W_rel : W_obj;
        const float* bo = (i == 1) ? b_rel : b_obj;
        skinny_mfma<true><<<Vv / 16, 64, 0, stream>>>(h2cur, (const void*)Wo, bo,
                                                      logits, Vv);
        log_softmax_k<<<64, 256, 0, stream>>>(logits, out, i);
    }
}

// Round 8
// 655.293 us; speedup vs baseline: 1.7419x; 1.0369x over previous
//
#include <hip/hip_runtime.h>
#include <math.h>

#define Bsz 64
#define Tt  32
#define Dv  2048
#define Hd  1024
#define G3  3072
#define Vv  20000
#define ML  3

typedef __attribute__((ext_vector_type(8))) short bf16x8;
typedef __attribute__((ext_vector_type(4))) float f32x4;
typedef unsigned long long u64;
#define MFMA(a,b,c) __builtin_amdgcn_mfma_f32_16x16x32_bf16(a,b,c,0,0,0)

__device__ __forceinline__ short f2bf(float f) {
    union { float f; unsigned u; } v; v.f = f;
    unsigned r = v.u + 0x7fffu + ((v.u >> 16) & 1u);
    return (short)(r >> 16);
}
__device__ __forceinline__ float bf2f(short s) {
    union { unsigned u; float f; } v; v.u = ((unsigned)(unsigned short)s) << 16;
    return v.f;
}
__device__ __forceinline__ void cvt8(const float* __restrict__ s,
                                     short* __restrict__ d) {
    float4 x = *(const float4*)s;
    float4 y = *(const float4*)(s + 4);
    bf16x8 o;
    o[0]=f2bf(x.x); o[1]=f2bf(x.y); o[2]=f2bf(x.z); o[3]=f2bf(x.w);
    o[4]=f2bf(y.x); o[5]=f2bf(y.y); o[6]=f2bf(y.z); o[7]=f2bf(y.w);
    *(bf16x8*)d = o;
}

// One wave (64 lanes) polls 64 per-block flags until all >= tgt.
__device__ __forceinline__ void poll_flags(const unsigned* fl, unsigned tgt) {
    const int lane = threadIdx.x & 63;
    unsigned f = __hip_atomic_load(&fl[lane], __ATOMIC_RELAXED,
                                   __HIP_MEMORY_SCOPE_AGENT);
    while (!__all((int)(f >= tgt))) {
        __builtin_amdgcn_s_sleep(2);
        f = __hip_atomic_load(&fl[lane], __ATOMIC_RELAXED,
                              __HIP_MEMORY_SCOPE_AGENT);
    }
}

// ---------------------------------------------------------------------------
// Fused fp32->bf16 conversion of all encoder inputs (5 jobs, one launch).
// ---------------------------------------------------------------------------
__global__ __launch_bounds__(256)
void cvt_all(const float* __restrict__ vid,   short* __restrict__ vid_bf,
             const float* __restrict__ Wih1,  short* __restrict__ Wih1_bf,
             const float* __restrict__ Whh1,  short* __restrict__ Whh1_bf,
             const float* __restrict__ Whh2,  short* __restrict__ Whh2_bf,
             const float* __restrict__ Wih2,  short* __restrict__ Wih2c_bf)
{
    const long b0 = 524288;            // vid     2048*2048/8
    const long b1 = b0 + 786432;       // W_ih1   3072*2048/8
    const long b2 = b1 + 393216;       // W_hh1   3072*1024/8
    const long b3 = b2 + 393216;       // W_hh2
    const long b4 = b3 + 393216;       // W_ih2 slice (cols 0..1023 of 1536)
    for (long i = (long)blockIdx.x * 256 + threadIdx.x; i < b4;
         i += (long)gridDim.x * 256) {
        if (i < b0) {
            cvt8(vid + i * 8, vid_bf + i * 8);
        } else if (i < b1) {
            const long q = i - b0;
            cvt8(Wih1 + q * 8, Wih1_bf + q * 8);
        } else if (i < b2) {
            const long q = i - b1;
            cvt8(Whh1 + q * 8, Whh1_bf + q * 8);
        } else if (i < b3) {
            const long q = i - b2;
            cvt8(Whh2 + q * 8, Whh2_bf + q * 8);
        } else {
            const long q = i - b3;
            const long r = q >> 7, c = q & 127;          // 128 chunks/row
            cvt8(Wih2 + r * 1536 + c * 8, Wih2c_bf + r * 1024 + c * 8);
        }
    }
}

// ---------------------------------------------------------------------------
// Big MFMA GEMM (unchanged): C[M,N] = A*W^T + bias, 128x128 tile.
// ---------------------------------------------------------------------------
__global__ __launch_bounds__(256)
void gemm_mfma_128(const short* __restrict__ A, int lda,
                   const short* __restrict__ W, int ldw,
                   const float* __restrict__ bias,
                   float* __restrict__ C, int ldc, int K)
{
    __shared__ __align__(16) short As[128 * 40];
    __shared__ __align__(16) short Bs[128 * 40];
    const int tid = threadIdx.x;
    const int w = tid >> 6, l = tid & 63;
    const int wm = w >> 1, wn = w & 1;
    const int lr = l & 15, lg = l >> 4;
    const int m0 = blockIdx.y * 128, n0 = blockIdx.x * 128;
    const int sm = tid >> 2;
    const int skg = tid & 3;

    f32x4 acc[4][4] = {};

    for (int k0 = 0; k0 < K; k0 += 32) {
        #pragma unroll
        for (int i = 0; i < 2; ++i) {
            const int m = i * 64 + sm;
            bf16x8 av = *(const bf16x8*)(A + (size_t)(m0 + m) * lda + k0 + skg * 8);
            bf16x8 wv = *(const bf16x8*)(W + (size_t)(n0 + m) * ldw + k0 + skg * 8);
            *(bf16x8*)(As + m * 40 + skg * 8) = av;
            *(bf16x8*)(Bs + m * 40 + skg * 8) = wv;
        }
        __syncthreads();
        bf16x8 af[4], bfr[4];
        #pragma unroll
        for (int mt = 0; mt < 4; ++mt) {
            const int m = wm * 64 + mt * 16 + lr;
            const int n = wn * 64 + mt * 16 + lr;
            af[mt]  = *(const bf16x8*)(As + m * 40 + lg * 8);
            bfr[mt] = *(const bf16x8*)(Bs + n * 40 + lg * 8);
        }
        #pragma unroll
        for (int mt = 0; mt < 4; ++mt)
            #pragma unroll
            for (int nt = 0; nt < 4; ++nt)
                acc[mt][nt] = MFMA(af[mt], bfr[nt], acc[mt][nt]);
        __syncthreads();
    }

    #pragma unroll
    for (int mt = 0; mt < 4; ++mt)
        #pragma unroll
        for (int nt = 0; nt < 4; ++nt)
            #pragma unroll
            for (int v = 0; v < 4; ++v) {
                const int m = m0 + wm * 64 + mt * 16 + lg * 4 + v;
                const int n = n0 + wn * 64 + nt * 16 + lr;
                C[(size_t)m * ldc + n] = acc[mt][nt][v] + bias[n];
            }
}

// ---------------------------------------------------------------------------
// Fused encoder pipeline: 256 blocks = 4 groups of 64.
//   role 0 (G1): layer-1 GRU; role 1 (GP): xp2 projection; role 2 (G2):
//   layer-2 GRU (as round 7). role 3: fp32->bf16 conversion of W_obj/W_rel
//   (bandwidth-free under the latency-bound pipeline; gated by do_cvt).
// Roles 0-2 are launched first (blocks 0..191) so their co-residency is
// unchanged; role 3 has no dependencies either way.
// ---------------------------------------------------------------------------
__global__ __launch_bounds__(256, 1)
void enc_pipeline(const float* __restrict__ xp1,
                  const short* __restrict__ Whh1, const float* __restrict__ b_hh1,
                  const short* __restrict__ Wih2, const float* __restrict__ b_ih2,
                  const short* __restrict__ Whh2, const float* __restrict__ b_hh2,
                  short* __restrict__ out1h,   // (33,64,1024) bf16, slot0 = 0
                  float* __restrict__ xp2s,    // (32,64,3072) fp32
                  short* __restrict__ h2h,     // (33,64,1024) bf16, slot0 = 0
                  short* __restrict__ h1fin, short* __restrict__ h2fin,
                  unsigned* __restrict__ flags1, unsigned* __restrict__ flagsP,
                  unsigned* __restrict__ flags2,
                  const float* __restrict__ Wobj_src,
                  const float* __restrict__ Wrel_src,
                  short* __restrict__ Wobj_bf, short* __restrict__ Wrel_bf,
                  int do_cvt)
{
    __shared__ __align__(16) short Wl[4 * 3 * 8 * 64 * 8];   // 98304 B
    __shared__ __align__(16) float xch[4][4][3][256];        // 49152 B
    __shared__ __align__(16) short hstage[64][16];           // 2048 B
    const int tid = threadIdx.x;
    const int w  = tid >> 6;
    const int l  = tid & 63;
    const int lr = l & 15, lg = l >> 4;
    const int role = blockIdx.x >> 6;         // 0=G1, 1=GP, 2=G2, 3=cvt
    const int k    = blockIdx.x & 63;

    if (role == 3) {
        if (do_cvt) {
            const long NC = 2560000L;         // 20000*1024/8
            for (long i = (long)k * 256 + tid; i < 2 * NC; i += 64 * 256) {
                if (i < NC) cvt8(Wobj_src + i * 8, Wobj_bf + i * 8);
                else {
                    const long q = i - NC;
                    cvt8(Wrel_src + q * 8, Wrel_bf + q * 8);
                }
            }
        }
        return;
    }

    const int j0 = k * 16;
    const int j  = j0 + lr;

    const short* Wsrc = (role == 0) ? Whh1 : (role == 1) ? Wih2 : Whh2;
    const float* bias = (role == 0) ? b_hh1 : (role == 1) ? b_ih2 : b_hh2;

    // ---- stage W slice into LDS, fragment-linear (once) ----
    #pragma unroll
    for (int g = 0; g < 3; ++g)
        #pragma unroll
        for (int ks = 0; ks < 8; ++ks) {
            bf16x8 v = *(const bf16x8*)(Wsrc + (size_t)(g * Hd + j) * Hd
                                        + w * 256 + ks * 32 + lg * 8);
            *(bf16x8*)(Wl + ((((w * 3 + g) * 8 + ks) * 64) + l) * 8) = v;
        }

    const float b0 = bias[j], b1 = bias[Hd + j], b2 = bias[2 * Hd + j];
    short* Ab = (role == 2) ? h2h : out1h;
    short* hfin = (role == 0) ? h1fin : h2fin;

    float hp[4] = {0.f, 0.f, 0.f, 0.f};
    float xr[4], xz[4], xn[4];
    if (role == 0) {
        #pragma unroll
        for (int v = 0; v < 4; ++v) {
            const int b = w * 16 + lg * 4 + v;
            const float* xrow = xp1 + (size_t)(b * Tt) * G3;
            xr[v] = xrow[j]; xz[v] = xrow[Hd + j]; xn[v] = xrow[2 * Hd + j];
        }
    }
    __syncthreads();   // Wl ready

    for (int t = 0; t < Tt; ++t) {
        if (role == 0)      { if (w == 0) poll_flags(flags1, (unsigned)t); }
        else if (role == 1) { if (w == 0) poll_flags(flags1, (unsigned)(t + 1)); }
        else {
            if (w == 0)      poll_flags(flagsP, (unsigned)(t + 1));
            else if (w == 1) poll_flags(flags2, (unsigned)t);
        }
        __syncthreads();
        asm volatile("" ::: "memory");

        const short* hin = Ab + (size_t)(role == 1 ? t + 1 : t) * (64 * Hd);
        bf16x8 A[4][8];
        #pragma unroll
        for (int mt = 0; mt < 4; ++mt)
            #pragma unroll
            for (int ks = 0; ks < 8; ++ks)
                A[mt][ks] = *(const bf16x8*)(hin + (size_t)(mt * 16 + lr) * Hd
                                             + w * 256 + ks * 32 + lg * 8);
        if (role == 2) {
            #pragma unroll
            for (int v = 0; v < 4; ++v) {
                const int b = w * 16 + lg * 4 + v;
                const float* xrow = xp2s + ((size_t)t * 64 + b) * G3;
                xr[v] = xrow[j]; xz[v] = xrow[Hd + j]; xn[v] = xrow[2 * Hd + j];
            }
        }

        f32x4 acc[4][3] = {};
        #pragma unroll
        for (int ks = 0; ks < 8; ++ks) {
            bf16x8 B0 = *(const bf16x8*)(Wl + ((((w * 3 + 0) * 8 + ks) * 64) + l) * 8);
            bf16x8 B1 = *(const bf16x8*)(Wl + ((((w * 3 + 1) * 8 + ks) * 64) + l) * 8);
            bf16x8 B2 = *(const bf16x8*)(Wl + ((((w * 3 + 2) * 8 + ks) * 64) + l) * 8);
            #pragma unroll
            for (int mt = 0; mt < 4; ++mt) {
                acc[mt][0] = MFMA(A[mt][ks], B0, acc[mt][0]);
                acc[mt][1] = MFMA(A[mt][ks], B1, acc[mt][1]);
                acc[mt][2] = MFMA(A[mt][ks], B2, acc[mt][2]);
            }
        }

        #pragma unroll
        for (int mt = 0; mt < 4; ++mt)
            #pragma unroll
            for (int g = 0; g < 3; ++g)
                *(f32x4*)&xch[w][mt][g][l * 4] = acc[mt][g];
        __syncthreads();
        f32x4 tot[3];
        #pragma unroll
        for (int g = 0; g < 3; ++g) {
            f32x4 t0 = *(const f32x4*)&xch[0][w][g][l * 4];
            f32x4 t1 = *(const f32x4*)&xch[1][w][g][l * 4];
            f32x4 t2 = *(const f32x4*)&xch[2][w][g][l * 4];
            f32x4 t3 = *(const f32x4*)&xch[3][w][g][l * 4];
            tot[g] = (t0 + t1) + (t2 + t3);
        }

        if (role == 1) {
            const float bg[3] = {b0, b1, b2};
            #pragma unroll
            for (int v = 0; v < 4; ++v) {
                const int b = w * 16 + lg * 4 + v;
                #pragma unroll
                for (int g = 0; g < 3; ++g) {
                    union { float f; unsigned u; } cv;
                    cv.f = tot[g][v] + bg[g];
                    __hip_atomic_store(
                        (unsigned*)(xp2s + ((size_t)t * 64 + b) * G3 + g * Hd + j),
                        cv.u, __ATOMIC_RELAXED, __HIP_MEMORY_SCOPE_AGENT);
                }
            }
            __syncthreads();
        } else {
            #pragma unroll
            for (int v = 0; v < 4; ++v) {
                const int b = w * 16 + lg * 4 + v;
                const float rg = 1.f / (1.f + __expf(-(xr[v] + tot[0][v] + b0)));
                const float zg = 1.f / (1.f + __expf(-(xz[v] + tot[1][v] + b1)));
                const float ng = tanhf(xn[v] + rg * (tot[2][v] + b2));
                const float hv = (1.f - zg) * ng + zg * hp[v];
                hp[v] = hv;
                hstage[b][lr] = f2bf(hv);
            }
            if (role == 0 && t != Tt - 1) {
                #pragma unroll
                for (int v = 0; v < 4; ++v) {
                    const int b = w * 16 + lg * 4 + v;
                    const float* xrow = xp1 + (size_t)(b * Tt + t + 1) * G3;
                    xr[v] = xrow[j]; xz[v] = xrow[Hd + j]; xn[v] = xrow[2 * Hd + j];
                }
            }
            __syncthreads();

            {
                const int b = tid >> 2, part = tid & 3;
                const u64 pv = *(const u64*)&hstage[b][part * 4];
                __hip_atomic_store(
                    (u64*)(Ab + (size_t)(t + 1) * (64 * Hd) + b * Hd + j0 + part * 4),
                    pv, __ATOMIC_RELAXED, __HIP_MEMORY_SCOPE_AGENT);
                if (t == Tt - 1)
                    *(u64*)(hfin + (size_t)b * Hd + j0 + part * 4) = pv;
            }
            __syncthreads();
        }

        if (tid == 0) {
            unsigned* fl = (role == 0) ? flags1 : (role == 1) ? flagsP : flags2;
            __hip_atomic_store(&fl[k], (unsigned)(t + 1),
                               __ATOMIC_RELAXED, __HIP_MEMORY_SCOPE_AGENT);
        }
    }
}

// ---------------------------------------------------------------------------
// Decode GRU step (single step; kernel boundary = sync; plain loads/stores).
// 64 blocks x 256 thr; block owns 16 gate-cols; wave w owns K-quarter.
// ---------------------------------------------------------------------------
__global__ __launch_bounds__(256, 1)
void gru_step_dec(const float* __restrict__ xp, int xp_rs,
                  const short* __restrict__ Whh, const float* __restrict__ b_hh,
                  const short* __restrict__ h_in, short* __restrict__ h_out)
{
    __shared__ __align__(16) short Wl[4 * 3 * 8 * 64 * 8];
    __shared__ __align__(16) float xch[4][4][3][256];
    const int tid = threadIdx.x;
    const int w  = tid >> 6;
    const int l  = tid & 63;
    const int lr = l & 15, lg = l >> 4;
    const int j0 = blockIdx.x * 16;
    const int j  = j0 + lr;

    #pragma unroll
    for (int g = 0; g < 3; ++g)
        #pragma unroll
        for (int ks = 0; ks < 8; ++ks) {
            bf16x8 v = *(const bf16x8*)(Whh + (size_t)(g * Hd + j) * Hd
                                        + w * 256 + ks * 32 + lg * 8);
            *(bf16x8*)(Wl + ((((w * 3 + g) * 8 + ks) * 64) + l) * 8) = v;
        }

    bf16x8 A[4][8];
    #pragma unroll
    for (int mt = 0; mt < 4; ++mt)
        #pragma unroll
        for (int ks = 0; ks < 8; ++ks)
            A[mt][ks] = *(const bf16x8*)(h_in + (size_t)(mt * 16 + lr) * Hd
                                         + w * 256 + ks * 32 + lg * 8);
    __syncthreads();

    f32x4 acc[4][3] = {};
    #pragma unroll
    for (int ks = 0; ks < 8; ++ks) {
        bf16x8 B0 = *(const bf16x8*)(Wl + ((((w * 3 + 0) * 8 + ks) * 64) + l) * 8);
        bf16x8 B1 = *(const bf16x8*)(Wl + ((((w * 3 + 1) * 8 + ks) * 64) + l) * 8);
        bf16x8 B2 = *(const bf16x8*)(Wl + ((((w * 3 + 2) * 8 + ks) * 64) + l) * 8);
        #pragma unroll
        for (int mt = 0; mt < 4; ++mt) {
            acc[mt][0] = MFMA(A[mt][ks], B0, acc[mt][0]);
            acc[mt][1] = MFMA(A[mt][ks], B1, acc[mt][1]);
            acc[mt][2] = MFMA(A[mt][ks], B2, acc[mt][2]);
        }
    }

    #pragma unroll
    for (int mt = 0; mt < 4; ++mt)
        #pragma unroll
        for (int g = 0; g < 3; ++g)
            *(f32x4*)&xch[w][mt][g][l * 4] = acc[mt][g];
    __syncthreads();
    f32x4 tot[3];
    #pragma unroll
    for (int g = 0; g < 3; ++g) {
        f32x4 t0 = *(const f32x4*)&xch[0][w][g][l * 4];
        f32x4 t1 = *(const f32x4*)&xch[1][w][g][l * 4];
        f32x4 t2 = *(const f32x4*)&xch[2][w][g][l * 4];
        f32x4 t3 = *(const f32x4*)&xch[3][w][g][l * 4];
        tot[g] = (t0 + t1) + (t2 + t3);
    }

    const float bh0 = b_hh[j], bh1 = b_hh[Hd + j], bh2 = b_hh[2 * Hd + j];
    #pragma unroll
    for (int v = 0; v < 4; ++v) {
        const int b = w * 16 + lg * 4 + v;
        const float* xrow = xp + (size_t)(b * xp_rs) * G3;
        const float rg = 1.f / (1.f + __expf(-(xrow[j] + tot[0][v] + bh0)));
        const float zg = 1.f / (1.f + __expf(-(xrow[Hd + j] + tot[1][v] + bh1)));
        const float ng = tanhf(xrow[2 * Hd + j] + rg * (tot[2][v] + bh2));
        const float hpv = bf2f(h_in[(size_t)b * Hd + j]);
        h_out[(size_t)b * Hd + j] = f2bf((1.f - zg) * ng + zg * hpv);
    }
}

// ---------------------------------------------------------------------------
// 4-wave skinny GEMM: C[64,N]f32 = A[64,1024]bf16 * W[N,1024]^T + bias.
// A staged once to LDS (fragment-linear, conflict-free); wave w handles
// 16-col tile blockIdx*4+w with 4-deep W prefetch. WBF16: W bf16 else fp32.
// ---------------------------------------------------------------------------
template<bool WBF16>
__global__ __launch_bounds__(256, 1)
void skinny4(const short* __restrict__ A,
             const void* __restrict__ Wp,
             const float* __restrict__ bias,
             float* __restrict__ C, int N, int ntiles)
{
    __shared__ __align__(16) short Al[64 * 1024];   // 128 KB
    const int tid = threadIdx.x;
    const int w = tid >> 6, l = tid & 63;
    const int lr = l & 15, lg = l >> 4;

    #pragma unroll
    for (int i = 0; i < 32; ++i) {
        const int c = tid + i * 256;
        const int mt = c >> 11;
        const int ks = (c >> 6) & 31;
        const int cl = c & 63;
        bf16x8 v = *(const bf16x8*)(A + (size_t)(mt * 16 + (cl & 15)) * Hd
                                    + ks * 32 + (cl >> 4) * 8);
        *(bf16x8*)(Al + c * 8) = v;
    }
    __syncthreads();

    const int tile = blockIdx.x * 4 + w;
    if (tile >= ntiles) return;
    const int n0 = tile * 16;

    auto ldW = [&](int ks) -> bf16x8 {
        if constexpr (WBF16) {
            return *(const bf16x8*)((const short*)Wp + (size_t)(n0 + lr) * Hd
                                    + ks * 32 + lg * 8);
        } else {
            const float* p = (const float*)Wp + (size_t)(n0 + lr) * Hd
                             + ks * 32 + lg * 8;
            float4 x = *(const float4*)p;
            float4 y = *(const float4*)(p + 4);
            bf16x8 r;
            r[0]=f2bf(x.x); r[1]=f2bf(x.y); r[2]=f2bf(x.z); r[3]=f2bf(x.w);
            r[4]=f2bf(y.x); r[5]=f2bf(y.y); r[6]=f2bf(y.z); r[7]=f2bf(y.w);
            return r;
        }
    };
    auto ldA = [&](int mt, int ks) {
        return *(const bf16x8*)(Al + ((mt * 32 + ks) * 64 + l) * 8);
    };

    f32x4 acc[4] = {};
    bf16x8 Wf[4];
    #pragma unroll
    for (int i = 0; i < 4; ++i) Wf[i] = ldW(i);
    bf16x8 Ac[4];
    #pragma unroll
    for (int mt = 0; mt < 4; ++mt) Ac[mt] = ldA(mt, 0);

    #pragma unroll
    for (int ks = 0; ks < 32; ++ks) {
        bf16x8 An[4];
        if (ks < 31) {
            #pragma unroll
            for (int mt = 0; mt < 4; ++mt) An[mt] = ldA(mt, ks + 1);
        }
        const bf16x8 wcur = Wf[ks & 3];
        if (ks < 28) Wf[ks & 3] = ldW(ks + 4);
        #pragma unroll
        for (int mt = 0; mt < 4; ++mt)
            acc[mt] = MFMA(Ac[mt], wcur, acc[mt]);
        if (ks < 31) {
            #pragma unroll
            for (int mt = 0; mt < 4; ++mt) Ac[mt] = An[mt];
        }
    }

    const float bn = bias[n0 + lr];
    #pragma unroll
    for (int mt = 0; mt < 4; ++mt)
        #pragma unroll
        for (int v = 0; v < 4; ++v)
            C[(size_t)(mt * 16 + lg * 4 + v) * N + n0 + lr] = acc[mt][v] + bn;
}

// ---------------------------------------------------------------------------
// Row log-softmax over V=20000, out[b][step][v].
// ---------------------------------------------------------------------------
__global__ __launch_bounds__(256)
void log_softmax_k(const float* __restrict__ logits, float* __restrict__ out, int step)
{
    __shared__ float red[4];
    const int b   = blockIdx.x;
    const int tid = threadIdx.x;
    const float* row = logits + (size_t)b * Vv;

    float m = -1e30f;
    for (int v = tid; v < Vv; v += 256) m = fmaxf(m, row[v]);
    #pragma unroll
    for (int off = 32; off > 0; off >>= 1) m = fmaxf(m, __shfl_down(m, off, 64));
    if ((tid & 63) == 0) red[tid >> 6] = m;
    __syncthreads();
    m = fmaxf(fmaxf(red[0], red[1]), fmaxf(red[2], red[3]));
    __syncthreads();

    float s = 0.f;
    for (int v = tid; v < Vv; v += 256) s += expf(row[v] - m);
    #pragma unroll
    for (int off = 32; off > 0; off >>= 1) s += __shfl_down(s, off, 64);
    if ((tid & 63) == 0) red[tid >> 6] = s;
    __syncthreads();
    s = red[0] + red[1] + red[2] + red[3];
    const float lse = m + logf(s);

    float* orow = out + ((size_t)b * ML + step) * Vv;
    for (int v = tid; v < Vv; v += 256) orow[v] = row[v] - lse;
}

// ---------------------------------------------------------------------------
extern "C" void kernel_launch(void* const* d_in, const int* in_sizes, int n_in,
                              void* d_out, int out_size, void* d_ws, size_t ws_size,
                              hipStream_t stream)
{
    (void)in_sizes; (void)n_in; (void)out_size;
    const float* vid   = (const float*)d_in[0];
    const float* W_ih1 = (const float*)d_in[1];
    const float* W_hh1 = (const float*)d_in[2];
    const float* b_ih1 = (const float*)d_in[3];
    const float* b_hh1 = (const float*)d_in[4];
    const float* W_ih2 = (const float*)d_in[5];
    const float* W_hh2 = (const float*)d_in[6];
    const float* b_ih2 = (const float*)d_in[7];
    const float* b_hh2 = (const float*)d_in[8];
    const float* W_obj = (const float*)d_in[9];
    const float* b_obj = (const float*)d_in[10];
    const float* W_rel = (const float*)d_in[11];
    const float* b_rel = (const float*)d_in[12];
    float* out = (float*)d_out;

    // workspace carve-up
    char* p = (char*)d_ws;
    short* vid_bf   = (short*)p; p += (size_t)2048 * Dv * 2;
    short* Wih1_bf  = (short*)p; p += (size_t)G3 * Dv * 2;
    short* Whh1_bf  = (short*)p; p += (size_t)G3 * Hd * 2;
    short* Wih2c_bf = (short*)p; p += (size_t)G3 * Hd * 2;
    short* Whh2_bf  = (short*)p; p += (size_t)G3 * Hd * 2;
    char* zz = p;
    short* h1a = (short*)p; p += (size_t)64 * Hd * 2;
    short* h1b = (short*)p; p += (size_t)64 * Hd * 2;
    short* h2a = (short*)p; p += (size_t)64 * Hd * 2;
    short* h2b = (short*)p; p += (size_t)64 * Hd * 2;
    unsigned int* bar = (unsigned int*)p; p += 4096;
    size_t zz_bytes = (size_t)(p - zz);
    short* out1h  = (short*)p; p += (size_t)33 * 64 * Hd * 2;
    short* h2h    = (short*)p; p += (size_t)33 * 64 * Hd * 2;
    float* xp1    = (float*)p; p += (size_t)2048 * G3 * 4;
    float* xp2s   = (float*)p; p += (size_t)32 * 64 * G3 * 4;
    float* xp2t   = (float*)p; p += (size_t)64 * G3 * 4;
    float* logits = (float*)p; p += (size_t)64 * Vv * 4;
    short* Wobj_bf = (short*)p; p += (size_t)Vv * Hd * 2;   // 40.96 MB
    short* Wrel_bf = (short*)p; p += (size_t)Vv * Hd * 2;   // 40.96 MB
    const int use_bf = ((size_t)(p - (char*)d_ws) <= ws_size) ? 1 : 0;

    unsigned* flags1 = bar;
    unsigned* flagsP = bar + 64;
    unsigned* flags2 = bar + 128;

    hipMemsetAsync(zz, 0, zz_bytes, stream);
    hipMemsetAsync(out1h, 0, (size_t)64 * Hd * 2, stream);
    hipMemsetAsync(h2h,   0, (size_t)64 * Hd * 2, stream);

    // one fused conversion launch (vid + 4 recurrent/projection weights)
    cvt_all<<<1024, 256, 0, stream>>>(vid, vid_bf, W_ih1, Wih1_bf,
                                      W_hh1, Whh1_bf, W_hh2, Whh2_bf,
                                      W_ih2, Wih2c_bf);

    // Phase 1: xp1 = vid @ W_ih1^T + b_ih1
    gemm_mfma_128<<<dim3(G3 / 128, 2048 / 128), 256, 0, stream>>>(
        vid_bf, Dv, Wih1_bf, Dv, b_ih1, xp1, G3, Dv);

    // Phase 2-4 fused encoder (+ role-3 W_obj/W_rel conversion)
    enc_pipeline<<<256, 256, 0, stream>>>(
        xp1, Whh1_bf, b_hh1, Wih2c_bf, b_ih2, Whh2_bf, b_hh2,
        out1h, xp2s, h2h, h1a, h2a, flags1, flagsP, flags2,
        W_obj, W_rel, Wobj_bf, Wrel_bf, use_bf);

    // Phase 5: decode
    short* h1c = h1a; short* h1n = h1b;
    short* h2c = h2a; short* h2n = h2b;
    for (int i = 0; i < ML; ++i) {
        gru_step_dec<<<64, 256, 0, stream>>>(b_ih1, 0, Whh1_bf, b_hh1, h1c, h1n);
        { short* t = h1c; h1c = h1n; h1n = t; }
        skinny4<true><<<48, 256, 0, stream>>>(h1c, (const void*)Wih2c_bf,
                                              b_ih2, xp2t, G3, G3 / 16);
        gru_step_dec<<<64, 256, 0, stream>>>(xp2t, 1, Whh2_bf, b_hh2, h2c, h2n);
        { short* t = h2c; h2c = h2n; h2n = t; }
        const float* bo = (i == 1) ? b_rel : b_obj;
        if (use_bf) {
            const short* Wo = (i == 1) ? Wrel_bf : Wobj_bf;
            skinny4<true><<<313, 256, 0, stream>>>(h2c, (const void*)Wo,
                                                   bo, logits, Vv, Vv / 16);
        } else {
            const float* Wo = (i == 1) ? W_rel : W_obj;
            skinny4<false><<<313, 256, 0, stream>>>(h2c, (const void*)Wo,
                                                    bo, logits, Vv, Vv / 16);
        }
        log_softmax_k<<<64, 256, 0, stream>>>(logits, out, i);
    }
}

// Round 9
// 627.493 us; speedup vs baseline: 1.8191x; 1.0443x over previous
//
#include <hip/hip_runtime.h>
#include <math.h>

#define Bsz 64
#define Tt  32
#define TTOT 35          // 32 encoder + 3 decode GRU steps
#define Dv  2048
#define Hd  1024
#define G3  3072
#define Vv  20000
#define ML  3
#define NTILE 1250       // 20000 / 16

typedef __attribute__((ext_vector_type(8))) short bf16x8;
typedef __attribute__((ext_vector_type(4))) float f32x4;
typedef unsigned long long u64;
#define MFMA(a,b,c) __builtin_amdgcn_mfma_f32_16x16x32_bf16(a,b,c,0,0,0)

__device__ __forceinline__ short f2bf(float f) {
    union { float f; unsigned u; } v; v.f = f;
    unsigned r = v.u + 0x7fffu + ((v.u >> 16) & 1u);
    return (short)(r >> 16);
}
__device__ __forceinline__ float bf2f(short s) {
    union { unsigned u; float f; } v; v.u = ((unsigned)(unsigned short)s) << 16;
    return v.f;
}
__device__ __forceinline__ void cvt8(const float* __restrict__ s,
                                     short* __restrict__ d) {
    float4 x = *(const float4*)s;
    float4 y = *(const float4*)(s + 4);
    bf16x8 o;
    o[0]=f2bf(x.x); o[1]=f2bf(x.y); o[2]=f2bf(x.z); o[3]=f2bf(x.w);
    o[4]=f2bf(y.x); o[5]=f2bf(y.y); o[6]=f2bf(y.z); o[7]=f2bf(y.w);
    *(bf16x8*)d = o;
}

// One wave polls 64 per-block flags until all >= tgt.
__device__ __forceinline__ void poll_flags(const unsigned* fl, unsigned tgt) {
    const int lane = threadIdx.x & 63;
    unsigned f = __hip_atomic_load(&fl[lane], __ATOMIC_RELAXED,
                                   __HIP_MEMORY_SCOPE_AGENT);
    while (!__all((int)(f >= tgt))) {
        __builtin_amdgcn_s_sleep(2);
        f = __hip_atomic_load(&fl[lane], __ATOMIC_RELAXED,
                              __HIP_MEMORY_SCOPE_AGENT);
    }
}

// ---------------------------------------------------------------------------
// Fused fp32->bf16 conversion of all encoder inputs (5 jobs, one launch).
// ---------------------------------------------------------------------------
__global__ __launch_bounds__(256)
void cvt_all(const float* __restrict__ vid,   short* __restrict__ vid_bf,
             const float* __restrict__ Wih1,  short* __restrict__ Wih1_bf,
             const float* __restrict__ Whh1,  short* __restrict__ Whh1_bf,
             const float* __restrict__ Whh2,  short* __restrict__ Whh2_bf,
             const float* __restrict__ Wih2,  short* __restrict__ Wih2c_bf)
{
    const long b0 = 524288;            // vid     2048*2048/8
    const long b1 = b0 + 786432;       // W_ih1   3072*2048/8
    const long b2 = b1 + 393216;       // W_hh1   3072*1024/8
    const long b3 = b2 + 393216;       // W_hh2
    const long b4 = b3 + 393216;       // W_ih2 slice (cols 0..1023 of 1536)
    for (long i = (long)blockIdx.x * 256 + threadIdx.x; i < b4;
         i += (long)gridDim.x * 256) {
        if (i < b0) {
            cvt8(vid + i * 8, vid_bf + i * 8);
        } else if (i < b1) {
            const long q = i - b0;
            cvt8(Wih1 + q * 8, Wih1_bf + q * 8);
        } else if (i < b2) {
            const long q = i - b1;
            cvt8(Whh1 + q * 8, Whh1_bf + q * 8);
        } else if (i < b3) {
            const long q = i - b2;
            cvt8(Whh2 + q * 8, Whh2_bf + q * 8);
        } else {
            const long q = i - b3;
            const long r = q >> 7, c = q & 127;
            cvt8(Wih2 + r * 1536 + c * 8, Wih2c_bf + r * 1024 + c * 8);
        }
    }
}

// ---------------------------------------------------------------------------
// Big MFMA GEMM (unchanged): C[M,N] = A*W^T + bias, 128x128 tile.
// ---------------------------------------------------------------------------
__global__ __launch_bounds__(256)
void gemm_mfma_128(const short* __restrict__ A, int lda,
                   const short* __restrict__ W, int ldw,
                   const float* __restrict__ bias,
                   float* __restrict__ C, int ldc, int K)
{
    __shared__ __align__(16) short As[128 * 40];
    __shared__ __align__(16) short Bs[128 * 40];
    const int tid = threadIdx.x;
    const int w = tid >> 6, l = tid & 63;
    const int wm = w >> 1, wn = w & 1;
    const int lr = l & 15, lg = l >> 4;
    const int m0 = blockIdx.y * 128, n0 = blockIdx.x * 128;
    const int sm = tid >> 2;
    const int skg = tid & 3;

    f32x4 acc[4][4] = {};

    for (int k0 = 0; k0 < K; k0 += 32) {
        #pragma unroll
        for (int i = 0; i < 2; ++i) {
            const int m = i * 64 + sm;
            bf16x8 av = *(const bf16x8*)(A + (size_t)(m0 + m) * lda + k0 + skg * 8);
            bf16x8 wv = *(const bf16x8*)(W + (size_t)(n0 + m) * ldw + k0 + skg * 8);
            *(bf16x8*)(As + m * 40 + skg * 8) = av;
            *(bf16x8*)(Bs + m * 40 + skg * 8) = wv;
        }
        __syncthreads();
        bf16x8 af[4], bfr[4];
        #pragma unroll
        for (int mt = 0; mt < 4; ++mt) {
            const int m = wm * 64 + mt * 16 + lr;
            const int n = wn * 64 + mt * 16 + lr;
            af[mt]  = *(const bf16x8*)(As + m * 40 + lg * 8);
            bfr[mt] = *(const bf16x8*)(Bs + n * 40 + lg * 8);
        }
        #pragma unroll
        for (int mt = 0; mt < 4; ++mt)
            #pragma unroll
            for (int nt = 0; nt < 4; ++nt)
                acc[mt][nt] = MFMA(af[mt], bfr[nt], acc[mt][nt]);
        __syncthreads();
    }

    #pragma unroll
    for (int mt = 0; mt < 4; ++mt)
        #pragma unroll
        for (int nt = 0; nt < 4; ++nt)
            #pragma unroll
            for (int v = 0; v < 4; ++v) {
                const int m = m0 + wm * 64 + mt * 16 + lg * 4 + v;
                const int n = n0 + wn * 64 + nt * 16 + lr;
                C[(size_t)m * ldc + n] = acc[mt][nt][v] + bias[n];
            }
}

// ---------------------------------------------------------------------------
// MEGAKERNEL: encoder pipeline + decode, one launch, 256 blocks.
// Phase 1 (roles 0-2 = blocks 0..191): 35 pipelined rounds.
//   role 0: GRU1. t<32: xp from xp1; t>=32: xp = b_ih1 (decode steps).
//           reads out1h[t], publishes out1h[t+1], flags1.
//   role 1: proj xp2[t] = out1h[t+1] @ W_ih2c^T + b_ih2 -> xp2s[t], flagsP.
//   role 2: GRU2. reads xp2s[t] + h2h[t], publishes h2h[t+1], flags2.
// Phase 2 (ALL 256 blocks): for i in 0..2, gated on flags2 >= 33+i:
//   logits_i = h2h[33+i] @ W_{obj|rel}^T + bias (fp32 W streamed, converted
//   in-register; 1250 16-col tiles over 1024 waves, full-K per wave, no LDS);
//   per-block flagL; role-3 blocks (idle in phase 1) then log-softmax row k
//   of logits_i into d_out. 3 separate logits buffers keep plain reads
//   first-touch-fresh.
// ---------------------------------------------------------------------------
__global__ __launch_bounds__(256, 1)
void mega(const float* __restrict__ xp1,
          const short* __restrict__ Whh1, const float* __restrict__ b_hh1,
          const float* __restrict__ b_ih1,
          const short* __restrict__ Wih2, const float* __restrict__ b_ih2,
          const short* __restrict__ Whh2, const float* __restrict__ b_hh2,
          short* __restrict__ out1h,   // (36,64,1024) bf16, slot0 = 0
          float* __restrict__ xp2s,    // (35,64,3072) fp32
          short* __restrict__ h2h,     // (36,64,1024) bf16, slot0 = 0
          unsigned* __restrict__ flags1, unsigned* __restrict__ flagsP,
          unsigned* __restrict__ flags2, unsigned* __restrict__ flagL,
          const float* __restrict__ Wobj, const float* __restrict__ bobj,
          const float* __restrict__ Wrel, const float* __restrict__ brel,
          float* __restrict__ logits3, float* __restrict__ out)
{
    __shared__ __align__(16) short Wl[4 * 3 * 8 * 64 * 8];   // 98304 B
    __shared__ __align__(16) float xch[4][4][3][256];        // 49152 B
    __shared__ __align__(16) short hstage[64][16];           // 2048 B
    const int tid = threadIdx.x;
    const int w  = tid >> 6;
    const int l  = tid & 63;
    const int lr = l & 15, lg = l >> 4;
    const int role = blockIdx.x >> 6;         // 0=GRU1, 1=proj, 2=GRU2, 3=softmax
    const int k    = blockIdx.x & 63;

    if (role < 3) {
        const int j0 = k * 16;
        const int j  = j0 + lr;
        const short* Wsrc = (role == 0) ? Whh1 : (role == 1) ? Wih2 : Whh2;
        const float* bias = (role == 0) ? b_hh1 : (role == 1) ? b_ih2 : b_hh2;

        // stage W slice into LDS, fragment-linear (once, reused all 35 rounds)
        #pragma unroll
        for (int g = 0; g < 3; ++g)
            #pragma unroll
            for (int ks = 0; ks < 8; ++ks) {
                bf16x8 v = *(const bf16x8*)(Wsrc + (size_t)(g * Hd + j) * Hd
                                            + w * 256 + ks * 32 + lg * 8);
                *(bf16x8*)(Wl + ((((w * 3 + g) * 8 + ks) * 64) + l) * 8) = v;
            }

        const float b0 = bias[j], b1 = bias[Hd + j], b2 = bias[2 * Hd + j];
        short* Ab = (role == 2) ? h2h : out1h;

        float bxr = 0.f, bxz = 0.f, bxn = 0.f;   // decode bias-xp (role 0)
        float hp[4] = {0.f, 0.f, 0.f, 0.f};
        float xr[4], xz[4], xn[4];
        if (role == 0) {
            bxr = b_ih1[j]; bxz = b_ih1[Hd + j]; bxn = b_ih1[2 * Hd + j];
            #pragma unroll
            for (int v = 0; v < 4; ++v) {
                const int b = w * 16 + lg * 4 + v;
                const float* xrow = xp1 + (size_t)(b * Tt) * G3;
                xr[v] = xrow[j]; xz[v] = xrow[Hd + j]; xn[v] = xrow[2 * Hd + j];
            }
        }
        __syncthreads();   // Wl ready

        for (int t = 0; t < TTOT; ++t) {
            if (role == 0)      { if (w == 0) poll_flags(flags1, (unsigned)t); }
            else if (role == 1) { if (w == 0) poll_flags(flags1, (unsigned)(t + 1)); }
            else {
                if (w == 0)      poll_flags(flagsP, (unsigned)(t + 1));
                else if (w == 1) poll_flags(flags2, (unsigned)t);
            }
            __syncthreads();
            asm volatile("" ::: "memory");

            const short* hin = Ab + (size_t)(role == 1 ? t + 1 : t) * (64 * Hd);
            bf16x8 A[4][8];
            #pragma unroll
            for (int mt = 0; mt < 4; ++mt)
                #pragma unroll
                for (int ks = 0; ks < 8; ++ks)
                    A[mt][ks] = *(const bf16x8*)(hin + (size_t)(mt * 16 + lr) * Hd
                                                 + w * 256 + ks * 32 + lg * 8);
            if (role == 2) {
                #pragma unroll
                for (int v = 0; v < 4; ++v) {
                    const int b = w * 16 + lg * 4 + v;
                    const float* xrow = xp2s + ((size_t)t * 64 + b) * G3;
                    xr[v] = xrow[j]; xz[v] = xrow[Hd + j]; xn[v] = xrow[2 * Hd + j];
                }
            }

            f32x4 acc[4][3] = {};
            #pragma unroll
            for (int ks = 0; ks < 8; ++ks) {
                bf16x8 B0 = *(const bf16x8*)(Wl + ((((w * 3 + 0) * 8 + ks) * 64) + l) * 8);
                bf16x8 B1 = *(const bf16x8*)(Wl + ((((w * 3 + 1) * 8 + ks) * 64) + l) * 8);
                bf16x8 B2 = *(const bf16x8*)(Wl + ((((w * 3 + 2) * 8 + ks) * 64) + l) * 8);
                #pragma unroll
                for (int mt = 0; mt < 4; ++mt) {
                    acc[mt][0] = MFMA(A[mt][ks], B0, acc[mt][0]);
                    acc[mt][1] = MFMA(A[mt][ks], B1, acc[mt][1]);
                    acc[mt][2] = MFMA(A[mt][ks], B2, acc[mt][2]);
                }
            }

            #pragma unroll
            for (int mt = 0; mt < 4; ++mt)
                #pragma unroll
                for (int g = 0; g < 3; ++g)
                    *(f32x4*)&xch[w][mt][g][l * 4] = acc[mt][g];
            __syncthreads();
            f32x4 tot[3];
            #pragma unroll
            for (int g = 0; g < 3; ++g) {
                f32x4 t0 = *(const f32x4*)&xch[0][w][g][l * 4];
                f32x4 t1 = *(const f32x4*)&xch[1][w][g][l * 4];
                f32x4 t2 = *(const f32x4*)&xch[2][w][g][l * 4];
                f32x4 t3 = *(const f32x4*)&xch[3][w][g][l * 4];
                tot[g] = (t0 + t1) + (t2 + t3);
            }

            if (role == 1) {
                const float bg[3] = {b0, b1, b2};
                #pragma unroll
                for (int v = 0; v < 4; ++v) {
                    const int b = w * 16 + lg * 4 + v;
                    #pragma unroll
                    for (int g = 0; g < 3; ++g) {
                        union { float f; unsigned u; } cv;
                        cv.f = tot[g][v] + bg[g];
                        __hip_atomic_store(
                            (unsigned*)(xp2s + ((size_t)t * 64 + b) * G3 + g * Hd + j),
                            cv.u, __ATOMIC_RELAXED, __HIP_MEMORY_SCOPE_AGENT);
                    }
                }
                __syncthreads();
            } else {
                #pragma unroll
                for (int v = 0; v < 4; ++v) {
                    const int b = w * 16 + lg * 4 + v;
                    const float rg = 1.f / (1.f + __expf(-(xr[v] + tot[0][v] + b0)));
                    const float zg = 1.f / (1.f + __expf(-(xz[v] + tot[1][v] + b1)));
                    const float ng = tanhf(xn[v] + rg * (tot[2][v] + b2));
                    const float hv = (1.f - zg) * ng + zg * hp[v];
                    hp[v] = hv;
                    hstage[b][lr] = f2bf(hv);
                }
                if (role == 0) {
                    if (t + 1 < Tt) {
                        #pragma unroll
                        for (int v = 0; v < 4; ++v) {
                            const int b = w * 16 + lg * 4 + v;
                            const float* xrow = xp1 + (size_t)(b * Tt + t + 1) * G3;
                            xr[v] = xrow[j]; xz[v] = xrow[Hd + j]; xn[v] = xrow[2 * Hd + j];
                        }
                    } else {   // decode steps: xp = b_ih1 broadcast
                        #pragma unroll
                        for (int v = 0; v < 4; ++v) { xr[v]=bxr; xz[v]=bxz; xn[v]=bxn; }
                    }
                }
                __syncthreads();

                {
                    const int b = tid >> 2, part = tid & 3;
                    const u64 pv = *(const u64*)&hstage[b][part * 4];
                    __hip_atomic_store(
                        (u64*)(Ab + (size_t)(t + 1) * (64 * Hd) + b * Hd + j0 + part * 4),
                        pv, __ATOMIC_RELAXED, __HIP_MEMORY_SCOPE_AGENT);
                }
                __syncthreads();
            }

            if (tid == 0) {
                unsigned* fl = (role == 0) ? flags1 : (role == 1) ? flagsP : flags2;
                __hip_atomic_store(&fl[k], (unsigned)(t + 1),
                                   __ATOMIC_RELAXED, __HIP_MEMORY_SCOPE_AGENT);
            }
        }
    }

    // ---- Phase 2: logits + log-softmax, all 256 blocks ----
    for (int i = 0; i < ML; ++i) {
        if (w == 0) poll_flags(flags2, (unsigned)(33 + i));
        __syncthreads();
        asm volatile("" ::: "memory");

        const float* Wo = (i == 1) ? Wrel : Wobj;
        const float* bo = (i == 1) ? brel : bobj;
        const short* h2p = h2h + (size_t)(33 + i) * (64 * Hd);
        float* lgp = logits3 + (size_t)i * 64 * Vv;

        for (int tg = blockIdx.x * 4 + w; tg < NTILE; tg += 1024) {
            const int n0 = tg * 16;
            f32x4 acc[4] = {};
            #pragma unroll 4
            for (int ks = 0; ks < 32; ++ks) {
                bf16x8 A0 = *(const bf16x8*)(h2p + (size_t)( 0 + lr) * Hd + ks * 32 + lg * 8);
                bf16x8 A1 = *(const bf16x8*)(h2p + (size_t)(16 + lr) * Hd + ks * 32 + lg * 8);
                bf16x8 A2 = *(const bf16x8*)(h2p + (size_t)(32 + lr) * Hd + ks * 32 + lg * 8);
                bf16x8 A3 = *(const bf16x8*)(h2p + (size_t)(48 + lr) * Hd + ks * 32 + lg * 8);
                const float* wp = Wo + (size_t)(n0 + lr) * Hd + ks * 32 + lg * 8;
                float4 x = *(const float4*)wp;
                float4 y = *(const float4*)(wp + 4);
                bf16x8 wv;
                wv[0]=f2bf(x.x); wv[1]=f2bf(x.y); wv[2]=f2bf(x.z); wv[3]=f2bf(x.w);
                wv[4]=f2bf(y.x); wv[5]=f2bf(y.y); wv[6]=f2bf(y.z); wv[7]=f2bf(y.w);
                acc[0] = MFMA(A0, wv, acc[0]);
                acc[1] = MFMA(A1, wv, acc[1]);
                acc[2] = MFMA(A2, wv, acc[2]);
                acc[3] = MFMA(A3, wv, acc[3]);
            }
            const float bn = bo[n0 + lr];
            #pragma unroll
            for (int mt = 0; mt < 4; ++mt)
                #pragma unroll
                for (int v = 0; v < 4; ++v) {
                    union { float f; unsigned u; } cv;
                    cv.f = acc[mt][v] + bn;
                    __hip_atomic_store(
                        (unsigned*)(lgp + (size_t)(mt * 16 + lg * 4 + v) * Vv + n0 + lr),
                        cv.u, __ATOMIC_RELAXED, __HIP_MEMORY_SCOPE_AGENT);
                }
        }
        __syncthreads();   // all waves' stores issued & acked (vmcnt drained)
        if (tid == 0)
            __hip_atomic_store(&flagL[blockIdx.x], (unsigned)(i + 1),
                               __ATOMIC_RELAXED, __HIP_MEMORY_SCOPE_AGENT);

        if (role == 3) {
            // wait for all 256 blocks' logits tiles (thread tid checks flagL[tid])
            for (;;) {
                int ok = (int)(__hip_atomic_load(&flagL[tid], __ATOMIC_RELAXED,
                                                 __HIP_MEMORY_SCOPE_AGENT)
                               >= (unsigned)(i + 1));
                if (__syncthreads_and(ok)) break;
                __builtin_amdgcn_s_sleep(2);
            }
            asm volatile("" ::: "memory");

            // log-softmax of row k
            float* red = (float*)xch;
            const float* row = lgp + (size_t)k * Vv;
            float m = -1e30f;
            for (int v = tid; v < Vv; v += 256) m = fmaxf(m, row[v]);
            #pragma unroll
            for (int off = 32; off > 0; off >>= 1) m = fmaxf(m, __shfl_down(m, off, 64));
            if (l == 0) red[w] = m;
            __syncthreads();
            m = fmaxf(fmaxf(red[0], red[1]), fmaxf(red[2], red[3]));
            __syncthreads();
            float s = 0.f;
            for (int v = tid; v < Vv; v += 256) s += expf(row[v] - m);
            #pragma unroll
            for (int off = 32; off > 0; off >>= 1) s += __shfl_down(s, off, 64);
            if (l == 0) red[w] = s;
            __syncthreads();
            s = red[0] + red[1] + red[2] + red[3];
            const float lse = m + logf(s);
            float* orow = out + ((size_t)k * ML + i) * Vv;
            for (int v = tid; v < Vv; v += 256) orow[v] = row[v] - lse;
            __syncthreads();   // red WAR before next iter
        }
    }
}

// ---------------------------------------------------------------------------
extern "C" void kernel_launch(void* const* d_in, const int* in_sizes, int n_in,
                              void* d_out, int out_size, void* d_ws, size_t ws_size,
                              hipStream_t stream)
{
    (void)in_sizes; (void)n_in; (void)out_size; (void)ws_size;
    const float* vid   = (const float*)d_in[0];
    const float* W_ih1 = (const float*)d_in[1];
    const float* W_hh1 = (const float*)d_in[2];
    const float* b_ih1 = (const float*)d_in[3];
    const float* b_hh1 = (const float*)d_in[4];
    const float* W_ih2 = (const float*)d_in[5];
    const float* W_hh2 = (const float*)d_in[6];
    const float* b_ih2 = (const float*)d_in[7];
    const float* b_hh2 = (const float*)d_in[8];
    const float* W_obj = (const float*)d_in[9];
    const float* b_obj = (const float*)d_in[10];
    const float* W_rel = (const float*)d_in[11];
    const float* b_rel = (const float*)d_in[12];
    float* out = (float*)d_out;

    // workspace carve-up (~118 MB)
    char* p = (char*)d_ws;
    short* vid_bf   = (short*)p; p += (size_t)2048 * Dv * 2;        // 8.0 MB
    short* Wih1_bf  = (short*)p; p += (size_t)G3 * Dv * 2;          // 12.6 MB
    short* Whh1_bf  = (short*)p; p += (size_t)G3 * Hd * 2;          // 6.3 MB
    short* Wih2c_bf = (short*)p; p += (size_t)G3 * Hd * 2;          // 6.3 MB
    short* Whh2_bf  = (short*)p; p += (size_t)G3 * Hd * 2;          // 6.3 MB
    unsigned int* flg = (unsigned int*)p; p += 4096;                // flags
    short* out1h  = (short*)p; p += (size_t)36 * 64 * Hd * 2;       // 4.7 MB
    short* h2h    = (short*)p; p += (size_t)36 * 64 * Hd * 2;       // 4.7 MB
    float* xp1    = (float*)p; p += (size_t)2048 * G3 * 4;          // 25.2 MB
    float* xp2s   = (float*)p; p += (size_t)TTOT * 64 * G3 * 4;     // 27.5 MB
    float* logits3= (float*)p; p += (size_t)ML * 64 * Vv * 4;       // 15.4 MB

    unsigned* flags1 = flg;
    unsigned* flagsP = flg + 64;
    unsigned* flags2 = flg + 128;
    unsigned* flagL  = flg + 256;   // 256 entries

    hipMemsetAsync(flg, 0, 4096, stream);
    hipMemsetAsync(out1h, 0, (size_t)64 * Hd * 2, stream);   // slot 0 = h1(-1)=0
    hipMemsetAsync(h2h,   0, (size_t)64 * Hd * 2, stream);   // slot 0 = h2(-1)=0

    // one fused conversion launch (vid + 4 recurrent/projection weights)
    cvt_all<<<1024, 256, 0, stream>>>(vid, vid_bf, W_ih1, Wih1_bf,
                                      W_hh1, Whh1_bf, W_hh2, Whh2_bf,
                                      W_ih2, Wih2c_bf);

    // Phase 1: xp1 = vid @ W_ih1^T + b_ih1
    gemm_mfma_128<<<dim3(G3 / 128, 2048 / 128), 256, 0, stream>>>(
        vid_bf, Dv, Wih1_bf, Dv, b_ih1, xp1, G3, Dv);

    // Everything else: one megakernel (encoder pipeline + decode + softmax)
    mega<<<256, 256, 0, stream>>>(
        xp1, Whh1_bf, b_hh1, b_ih1, Wih2c_bf, b_ih2, Whh2_bf, b_hh2,
        out1h, xp2s, h2h, flags1, flagsP, flags2, flagL,
        W_obj, b_obj, W_rel, b_rel, logits3, out);
}

// Round 10
// 554.835 us; speedup vs baseline: 2.0573x; 1.1310x over previous
//
#include <hip/hip_runtime.h>
#include <math.h>

#define Bsz 64
#define Tt  32
#define TTOT 35          // 32 encoder + 3 decode GRU steps
#define Dv  2048
#define Hd  1024
#define G3  3072
#define Vv  20000
#define ML  3
#define NTILE 1250       // 20000 / 16

typedef __attribute__((ext_vector_type(8))) short bf16x8;
typedef __attribute__((ext_vector_type(4))) float f32x4;
typedef unsigned long long u64;
#define MFMA(a,b,c) __builtin_amdgcn_mfma_f32_16x16x32_bf16(a,b,c,0,0,0)

__device__ __forceinline__ short f2bf(float f) {
    union { float f; unsigned u; } v; v.f = f;
    unsigned r = v.u + 0x7fffu + ((v.u >> 16) & 1u);
    return (short)(r >> 16);
}
__device__ __forceinline__ void cvt8(const float* __restrict__ s,
                                     short* __restrict__ d) {
    float4 x = *(const float4*)s;
    float4 y = *(const float4*)(s + 4);
    bf16x8 o;
    o[0]=f2bf(x.x); o[1]=f2bf(x.y); o[2]=f2bf(x.z); o[3]=f2bf(x.w);
    o[4]=f2bf(y.x); o[5]=f2bf(y.y); o[6]=f2bf(y.z); o[7]=f2bf(y.w);
    *(bf16x8*)d = o;
}
__device__ __forceinline__ bf16x8 pack8(const float* __restrict__ s) {
    float4 x = *(const float4*)s;
    float4 y = *(const float4*)(s + 4);
    bf16x8 o;
    o[0]=f2bf(x.x); o[1]=f2bf(x.y); o[2]=f2bf(x.z); o[3]=f2bf(x.w);
    o[4]=f2bf(y.x); o[5]=f2bf(y.y); o[6]=f2bf(y.z); o[7]=f2bf(y.w);
    return o;
}

// One wave polls 64 per-block flags until all >= tgt.
__device__ __forceinline__ void poll_flags(const unsigned* fl, unsigned tgt) {
    const int lane = threadIdx.x & 63;
    unsigned f = __hip_atomic_load(&fl[lane], __ATOMIC_RELAXED,
                                   __HIP_MEMORY_SCOPE_AGENT);
    while (!__all((int)(f >= tgt))) {
        __builtin_amdgcn_s_sleep(2);
        f = __hip_atomic_load(&fl[lane], __ATOMIC_RELAXED,
                              __HIP_MEMORY_SCOPE_AGENT);
    }
}

// ---------------------------------------------------------------------------
// fp32 -> bf16 conversion: vid + W_ih1 only (role blocks convert their own
// recurrent-weight slices in-register during LDS staging inside mega).
// ---------------------------------------------------------------------------
__global__ __launch_bounds__(256)
void cvt2(const float* __restrict__ vid,  short* __restrict__ vid_bf,
          const float* __restrict__ Wih1, short* __restrict__ Wih1_bf)
{
    const long b0 = 524288;            // vid   2048*2048/8
    const long b1 = b0 + 786432;       // W_ih1 3072*2048/8
    for (long i = (long)blockIdx.x * 256 + threadIdx.x; i < b1;
         i += (long)gridDim.x * 256) {
        if (i < b0) cvt8(vid + i * 8, vid_bf + i * 8);
        else { const long q = i - b0; cvt8(Wih1 + q * 8, Wih1_bf + q * 8); }
    }
}

// ---------------------------------------------------------------------------
// MEGAKERNEL: xp1 GEMM + encoder pipeline + decode GRU steps. 256 blocks.
//  blocks 192..255 (role 3): xp1 GEMM workers. xp1 is T-MAJOR (t*64+b, 3H) so
//    each 128-row m-tile = 2 complete timesteps. 384 tile-jobs (16 m x 24 n),
//    job = k + 64*jj -> earliest t-tiles complete first. A-row permutation:
//    vid row = (m&63)*32 + (m>>6). Epilogue: agent-scope atomic u32 stores
//    (cross-XCD visible); per-m-tile counter flagsG[mt] += 1 (done at 24).
//  blocks 0..191 (roles 0-2): 35 pipelined rounds as round 9.
//    role 0 (GRU1): round t<32 gates on flagsG[t>>1]==24 (wave 2 polls),
//    reads xp1[t*64+b]; t>=32 uses b_ih1 broadcast. role 1 (proj), role 2
//    (GRU2) unchanged. Roles stage W slices fp32->bf16 in-register into LDS
//    (W_ih2 has row stride 1536).
// Logits + softmax moved OUT (high-occupancy kernels; kernel boundary=sync).
// ---------------------------------------------------------------------------
__global__ __launch_bounds__(256, 1)
void mega(const short* __restrict__ vid_bf, const short* __restrict__ Wih1_bf,
          const float* __restrict__ b_ih1, float* __restrict__ xp1,
          const float* __restrict__ Whh1f, const float* __restrict__ b_hh1,
          const float* __restrict__ Wih2f, const float* __restrict__ b_ih2,
          const float* __restrict__ Whh2f, const float* __restrict__ b_hh2,
          short* __restrict__ out1h,   // (36,64,1024) bf16, slot0 = 0
          float* __restrict__ xp2s,    // (35,64,3072) fp32
          short* __restrict__ h2h,     // (36,64,1024) bf16, slot0 = 0
          unsigned* __restrict__ flags1, unsigned* __restrict__ flagsP,
          unsigned* __restrict__ flags2, unsigned* __restrict__ flagsG)
{
    __shared__ __align__(16) short Wl[4 * 3 * 8 * 64 * 8];   // 98304 B
    __shared__ __align__(16) float xch[4][4][3][256];        // 49152 B
    __shared__ __align__(16) short hstage[64][16];           // 2048 B
    const int tid = threadIdx.x;
    const int w  = tid >> 6;
    const int l  = tid & 63;
    const int lr = l & 15, lg = l >> 4;
    const int role = blockIdx.x >> 6;         // 0=GRU1, 1=proj, 2=GRU2, 3=GEMM
    const int k    = blockIdx.x & 63;

    if (role == 3) {
        // ---- xp1 GEMM worker: 6 jobs of 128x128 tiles, K=2048 ----
        short* As = Wl;                  // 128*40 shorts
        short* Bs = Wl + 128 * 40;
        const int wm = w >> 1, wn = w & 1;
        const int sm = tid >> 2;
        const int skg = tid & 3;
        for (int jj = 0; jj < 6; ++jj) {
            const int job = k + jj * 64;       // < 384 always
            const int mt0 = job / 24, nt0 = job % 24;
            const int m0 = mt0 * 128, n0 = nt0 * 128;
            f32x4 acc[4][4] = {};
            for (int k0 = 0; k0 < Dv; k0 += 32) {
                #pragma unroll
                for (int i = 0; i < 2; ++i) {
                    const int m = m0 + i * 64 + sm;
                    const int arow = (m & 63) * Tt + (m >> 6);   // t-major -> vid row
                    bf16x8 av = *(const bf16x8*)(vid_bf + (size_t)arow * Dv + k0 + skg * 8);
                    bf16x8 wv = *(const bf16x8*)(Wih1_bf + (size_t)(n0 + i * 64 + sm) * Dv + k0 + skg * 8);
                    *(bf16x8*)(As + (i * 64 + sm) * 40 + skg * 8) = av;
                    *(bf16x8*)(Bs + (i * 64 + sm) * 40 + skg * 8) = wv;
                }
                __syncthreads();
                bf16x8 af[4], bfr[4];
                #pragma unroll
                for (int mt = 0; mt < 4; ++mt) {
                    af[mt]  = *(const bf16x8*)(As + (wm * 64 + mt * 16 + lr) * 40 + lg * 8);
                    bfr[mt] = *(const bf16x8*)(Bs + (wn * 64 + mt * 16 + lr) * 40 + lg * 8);
                }
                #pragma unroll
                for (int mt = 0; mt < 4; ++mt)
                    #pragma unroll
                    for (int nt = 0; nt < 4; ++nt)
                        acc[mt][nt] = MFMA(af[mt], bfr[nt], acc[mt][nt]);
                __syncthreads();
            }
            #pragma unroll
            for (int mt = 0; mt < 4; ++mt)
                #pragma unroll
                for (int nt = 0; nt < 4; ++nt)
                    #pragma unroll
                    for (int v = 0; v < 4; ++v) {
                        const int m = m0 + wm * 64 + mt * 16 + lg * 4 + v;
                        const int n = n0 + wn * 64 + nt * 16 + lr;
                        union { float f; unsigned u; } cv;
                        cv.f = acc[mt][nt][v] + b_ih1[n];
                        __hip_atomic_store((unsigned*)(xp1 + (size_t)m * G3 + n),
                                           cv.u, __ATOMIC_RELAXED,
                                           __HIP_MEMORY_SCOPE_AGENT);
                    }
            __syncthreads();   // all 256 threads' stores acked
            if (tid == 0)
                __hip_atomic_fetch_add(&flagsG[mt0], 1u, __ATOMIC_RELAXED,
                                       __HIP_MEMORY_SCOPE_AGENT);
        }
        return;
    }

    // ---- roles 0-2: pipelined GRU/proj rounds ----
    const int j0 = k * 16;
    const int j  = j0 + lr;
    const float* Wf = (role == 0) ? Whh1f : (role == 1) ? Wih2f : Whh2f;
    const int ldw   = (role == 1) ? (Hd + 512) : Hd;
    const float* bias = (role == 0) ? b_hh1 : (role == 1) ? b_ih2 : b_hh2;

    // stage W slice into LDS, fp32 -> bf16 in-register, fragment-linear
    #pragma unroll
    for (int g = 0; g < 3; ++g)
        #pragma unroll
        for (int ks = 0; ks < 8; ++ks) {
            const float* src = Wf + (size_t)(g * Hd + j) * ldw + w * 256 + ks * 32 + lg * 8;
            *(bf16x8*)(Wl + ((((w * 3 + g) * 8 + ks) * 64) + l) * 8) = pack8(src);
        }

    const float b0 = bias[j], b1 = bias[Hd + j], b2 = bias[2 * Hd + j];
    short* Ab = (role == 2) ? h2h : out1h;

    float bxr = 0.f, bxz = 0.f, bxn = 0.f;
    if (role == 0) {
        bxr = b_ih1[j]; bxz = b_ih1[Hd + j]; bxn = b_ih1[2 * Hd + j];
    }
    float hp[4] = {0.f, 0.f, 0.f, 0.f};
    float xr[4], xz[4], xn[4];
    __syncthreads();   // Wl ready

    for (int t = 0; t < TTOT; ++t) {
        if (role == 0) {
            if (w == 0) poll_flags(flags1, (unsigned)t);
            else if (w == 2 && t < Tt) {
                const unsigned* fg = &flagsG[t >> 1];
                while (__hip_atomic_load(fg, __ATOMIC_RELAXED,
                                         __HIP_MEMORY_SCOPE_AGENT) < 24u)
                    __builtin_amdgcn_s_sleep(2);
            }
        } else if (role == 1) {
            if (w == 0) poll_flags(flags1, (unsigned)(t + 1));
        } else {
            if (w == 0)      poll_flags(flagsP, (unsigned)(t + 1));
            else if (w == 1) poll_flags(flags2, (unsigned)t);
        }
        __syncthreads();
        asm volatile("" ::: "memory");

        const short* hin = Ab + (size_t)(role == 1 ? t + 1 : t) * (64 * Hd);
        bf16x8 A[4][8];
        #pragma unroll
        for (int mt = 0; mt < 4; ++mt)
            #pragma unroll
            for (int ks = 0; ks < 8; ++ks)
                A[mt][ks] = *(const bf16x8*)(hin + (size_t)(mt * 16 + lr) * Hd
                                             + w * 256 + ks * 32 + lg * 8);
        if (role == 0) {
            if (t < Tt) {
                #pragma unroll
                for (int v = 0; v < 4; ++v) {
                    const int b = w * 16 + lg * 4 + v;
                    const float* xrow = xp1 + (size_t)(t * 64 + b) * G3;
                    xr[v] = xrow[j]; xz[v] = xrow[Hd + j]; xn[v] = xrow[2 * Hd + j];
                }
            } else {
                #pragma unroll
                for (int v = 0; v < 4; ++v) { xr[v]=bxr; xz[v]=bxz; xn[v]=bxn; }
            }
        } else if (role == 2) {
            #pragma unroll
            for (int v = 0; v < 4; ++v) {
                const int b = w * 16 + lg * 4 + v;
                const float* xrow = xp2s + ((size_t)t * 64 + b) * G3;
                xr[v] = xrow[j]; xz[v] = xrow[Hd + j]; xn[v] = xrow[2 * Hd + j];
            }
        }

        f32x4 acc[4][3] = {};
        #pragma unroll
        for (int ks = 0; ks < 8; ++ks) {
            bf16x8 B0 = *(const bf16x8*)(Wl + ((((w * 3 + 0) * 8 + ks) * 64) + l) * 8);
            bf16x8 B1 = *(const bf16x8*)(Wl + ((((w * 3 + 1) * 8 + ks) * 64) + l) * 8);
            bf16x8 B2 = *(const bf16x8*)(Wl + ((((w * 3 + 2) * 8 + ks) * 64) + l) * 8);
            #pragma unroll
            for (int mt = 0; mt < 4; ++mt) {
                acc[mt][0] = MFMA(A[mt][ks], B0, acc[mt][0]);
                acc[mt][1] = MFMA(A[mt][ks], B1, acc[mt][1]);
                acc[mt][2] = MFMA(A[mt][ks], B2, acc[mt][2]);
            }
        }

        #pragma unroll
        for (int mt = 0; mt < 4; ++mt)
            #pragma unroll
            for (int g = 0; g < 3; ++g)
                *(f32x4*)&xch[w][mt][g][l * 4] = acc[mt][g];
        __syncthreads();
        f32x4 tot[3];
        #pragma unroll
        for (int g = 0; g < 3; ++g) {
            f32x4 t0 = *(const f32x4*)&xch[0][w][g][l * 4];
            f32x4 t1 = *(const f32x4*)&xch[1][w][g][l * 4];
            f32x4 t2 = *(const f32x4*)&xch[2][w][g][l * 4];
            f32x4 t3 = *(const f32x4*)&xch[3][w][g][l * 4];
            tot[g] = (t0 + t1) + (t2 + t3);
        }

        if (role == 1) {
            const float bg[3] = {b0, b1, b2};
            #pragma unroll
            for (int v = 0; v < 4; ++v) {
                const int b = w * 16 + lg * 4 + v;
                #pragma unroll
                for (int g = 0; g < 3; ++g) {
                    union { float f; unsigned u; } cv;
                    cv.f = tot[g][v] + bg[g];
                    __hip_atomic_store(
                        (unsigned*)(xp2s + ((size_t)t * 64 + b) * G3 + g * Hd + j),
                        cv.u, __ATOMIC_RELAXED, __HIP_MEMORY_SCOPE_AGENT);
                }
            }
            __syncthreads();
        } else {
            #pragma unroll
            for (int v = 0; v < 4; ++v) {
                const int b = w * 16 + lg * 4 + v;
                const float rg = 1.f / (1.f + __expf(-(xr[v] + tot[0][v] + b0)));
                const float zg = 1.f / (1.f + __expf(-(xz[v] + tot[1][v] + b1)));
                const float ng = tanhf(xn[v] + rg * (tot[2][v] + b2));
                const float hv = (1.f - zg) * ng + zg * hp[v];
                hp[v] = hv;
                hstage[b][lr] = f2bf(hv);
            }
            __syncthreads();
            {
                const int b = tid >> 2, part = tid & 3;
                const u64 pv = *(const u64*)&hstage[b][part * 4];
                __hip_atomic_store(
                    (u64*)(Ab + (size_t)(t + 1) * (64 * Hd) + b * Hd + j0 + part * 4),
                    pv, __ATOMIC_RELAXED, __HIP_MEMORY_SCOPE_AGENT);
            }
            __syncthreads();
        }

        if (tid == 0) {
            unsigned* fl = (role == 0) ? flags1 : (role == 1) ? flagsP : flags2;
            __hip_atomic_store(&fl[k], (unsigned)(t + 1),
                               __ATOMIC_RELAXED, __HIP_MEMORY_SCOPE_AGENT);
        }
    }
}

// ---------------------------------------------------------------------------
// High-occupancy logits GEMM. Blocks 0..312: single pass over W_obj computes
// BOTH decode steps 0 and 2 (A = h2h[33], h2h[35]). Blocks 313..625: W_rel
// for step 1. No LDS, W streamed fp32->bf16 in-register, plain stores
// (consumed by next kernel launch). h2 matrices are L2-hot (128 KB each).
// ---------------------------------------------------------------------------
__global__ __launch_bounds__(256)
void logits_dual(const short* __restrict__ h2h,
                 const float* __restrict__ Wobj, const float* __restrict__ bobj,
                 const float* __restrict__ Wrel, const float* __restrict__ brel,
                 float* __restrict__ logits3)
{
    const int tid = threadIdx.x;
    const int w = tid >> 6, l = tid & 63;
    const int lr = l & 15, lg = l >> 4;
    const bool dual = blockIdx.x < 313;
    const int nb = dual ? blockIdx.x : blockIdx.x - 313;
    const int tile = nb * 4 + w;
    if (tile >= NTILE) return;
    const int n0 = tile * 16;
    const float* Wo = dual ? Wobj : Wrel;
    const float* bo = dual ? bobj : brel;
    const short* hA = h2h + (size_t)33 * 64 * Hd;
    const short* hB = h2h + (size_t)34 * 64 * Hd;
    const short* hC = h2h + (size_t)35 * 64 * Hd;

    f32x4 accA[4] = {}, accC[4] = {};
    const float* wbase = Wo + (size_t)(n0 + lr) * Hd + lg * 8;
    #pragma unroll 4
    for (int ks = 0; ks < 32; ++ks) {
        const bf16x8 wv = pack8(wbase + ks * 32);
        if (dual) {
            #pragma unroll
            for (int mt = 0; mt < 4; ++mt) {
                bf16x8 a = *(const bf16x8*)(hA + (size_t)(mt * 16 + lr) * Hd + ks * 32 + lg * 8);
                bf16x8 c = *(const bf16x8*)(hC + (size_t)(mt * 16 + lr) * Hd + ks * 32 + lg * 8);
                accA[mt] = MFMA(a, wv, accA[mt]);
                accC[mt] = MFMA(c, wv, accC[mt]);
            }
        } else {
            #pragma unroll
            for (int mt = 0; mt < 4; ++mt) {
                bf16x8 a = *(const bf16x8*)(hB + (size_t)(mt * 16 + lr) * Hd + ks * 32 + lg * 8);
                accA[mt] = MFMA(a, wv, accA[mt]);
            }
        }
    }

    const float bn = bo[n0 + lr];
    float* lg0 = logits3 + (size_t)(dual ? 0 : 1) * 64 * Vv;
    float* lg2 = logits3 + (size_t)2 * 64 * Vv;
    #pragma unroll
    for (int mt = 0; mt < 4; ++mt)
        #pragma unroll
        for (int v = 0; v < 4; ++v) {
            const size_t row = (size_t)(mt * 16 + lg * 4 + v) * Vv + n0 + lr;
            lg0[row] = accA[mt][v] + bn;
            if (dual) lg2[row] = accC[mt][v] + bn;
        }
}

// ---------------------------------------------------------------------------
// Row log-softmax for all 3 steps: grid 192 = (step, batch).
// ---------------------------------------------------------------------------
__global__ __launch_bounds__(256)
void log_softmax_all(const float* __restrict__ logits3, float* __restrict__ out)
{
    __shared__ float red[4];
    const int step = blockIdx.x >> 6;
    const int b    = blockIdx.x & 63;
    const int tid  = threadIdx.x;
    const float* row = logits3 + ((size_t)step * 64 + b) * Vv;

    float m = -1e30f;
    for (int v = tid; v < Vv; v += 256) m = fmaxf(m, row[v]);
    #pragma unroll
    for (int off = 32; off > 0; off >>= 1) m = fmaxf(m, __shfl_down(m, off, 64));
    if ((tid & 63) == 0) red[tid >> 6] = m;
    __syncthreads();
    m = fmaxf(fmaxf(red[0], red[1]), fmaxf(red[2], red[3]));
    __syncthreads();

    float s = 0.f;
    for (int v = tid; v < Vv; v += 256) s += expf(row[v] - m);
    #pragma unroll
    for (int off = 32; off > 0; off >>= 1) s += __shfl_down(s, off, 64);
    if ((tid & 63) == 0) red[tid >> 6] = s;
    __syncthreads();
    s = red[0] + red[1] + red[2] + red[3];
    const float lse = m + logf(s);

    float* orow = out + ((size_t)b * ML + step) * Vv;
    for (int v = tid; v < Vv; v += 256) orow[v] = row[v] - lse;
}

// ---------------------------------------------------------------------------
extern "C" void kernel_launch(void* const* d_in, const int* in_sizes, int n_in,
                              void* d_out, int out_size, void* d_ws, size_t ws_size,
                              hipStream_t stream)
{
    (void)in_sizes; (void)n_in; (void)out_size; (void)ws_size;
    const float* vid   = (const float*)d_in[0];
    const float* W_ih1 = (const float*)d_in[1];
    const float* W_hh1 = (const float*)d_in[2];
    const float* b_ih1 = (const float*)d_in[3];
    const float* b_hh1 = (const float*)d_in[4];
    const float* W_ih2 = (const float*)d_in[5];   // (3072,1536); cols 0..1023 used
    const float* W_hh2 = (const float*)d_in[6];
    const float* b_ih2 = (const float*)d_in[7];
    const float* b_hh2 = (const float*)d_in[8];
    const float* W_obj = (const float*)d_in[9];
    const float* b_obj = (const float*)d_in[10];
    const float* W_rel = (const float*)d_in[11];
    const float* b_rel = (const float*)d_in[12];
    float* out = (float*)d_out;

    // workspace carve-up (~98 MB)
    char* p = (char*)d_ws;
    short* vid_bf   = (short*)p; p += (size_t)2048 * Dv * 2;        // 8.0 MB
    short* Wih1_bf  = (short*)p; p += (size_t)G3 * Dv * 2;          // 12.6 MB
    unsigned int* flg = (unsigned int*)p; p += 4096;
    short* out1h  = (short*)p; p += (size_t)36 * 64 * Hd * 2;       // 4.7 MB
    short* h2h    = (short*)p; p += (size_t)36 * 64 * Hd * 2;       // 4.7 MB
    float* xp1    = (float*)p; p += (size_t)2048 * G3 * 4;          // 25.2 MB (t-major)
    float* xp2s   = (float*)p; p += (size_t)TTOT * 64 * G3 * 4;     // 27.5 MB
    float* logits3= (float*)p; p += (size_t)ML * 64 * Vv * 4;       // 15.4 MB

    unsigned* flags1 = flg;
    unsigned* flagsP = flg + 64;
    unsigned* flags2 = flg + 128;
    unsigned* flagsG = flg + 192;   // 16 m-tile counters

    hipMemsetAsync(flg, 0, 4096, stream);
    hipMemsetAsync(out1h, 0, (size_t)64 * Hd * 2, stream);   // slot 0 = h1(-1)=0
    hipMemsetAsync(h2h,   0, (size_t)64 * Hd * 2, stream);   // slot 0 = h2(-1)=0

    // convert vid + W_ih1 (everything else converted in-register)
    cvt2<<<640, 256, 0, stream>>>(vid, vid_bf, W_ih1, Wih1_bf);

    // megakernel: xp1 GEMM (role 3) + encoder pipeline + decode GRU steps
    mega<<<256, 256, 0, stream>>>(
        vid_bf, Wih1_bf, b_ih1, xp1,
        W_hh1, b_hh1, W_ih2, b_ih2, W_hh2, b_hh2,
        out1h, xp2s, h2h, flags1, flagsP, flags2, flagsG);

    // logits for all 3 decode steps (one W_obj pass covers steps 0 and 2)
    logits_dual<<<626, 256, 0, stream>>>(h2h, W_obj, b_obj, W_rel, b_rel, logits3);

    // log-softmax -> d_out
    log_softmax_all<<<192, 256, 0, stream>>>(logits3, out);
}

// Round 11
// 524.560 us; speedup vs baseline: 2.1760x; 1.0577x over previous
//
#include <hip/hip_runtime.h>
#include <math.h>

#define Bsz 64
#define Tt  32
#define TTOT 35          // 32 encoder + 3 decode GRU steps
#define Dv  2048
#define Hd  1024
#define G3  3072
#define Vv  20000
#define ML  3
#define NTILE 1250       // 20000 / 16

typedef __attribute__((ext_vector_type(8))) short bf16x8;
typedef __attribute__((ext_vector_type(4))) float f32x4;
typedef unsigned long long u64;
#define MFMA(a,b,c) __builtin_amdgcn_mfma_f32_16x16x32_bf16(a,b,c,0,0,0)

__device__ __forceinline__ short f2bf(float f) {
    union { float f; unsigned u; } v; v.f = f;
    unsigned r = v.u + 0x7fffu + ((v.u >> 16) & 1u);
    return (short)(r >> 16);
}
__device__ __forceinline__ void cvt8(const float* __restrict__ s,
                                     short* __restrict__ d) {
    float4 x = *(const float4*)s;
    float4 y = *(const float4*)(s + 4);
    bf16x8 o;
    o[0]=f2bf(x.x); o[1]=f2bf(x.y); o[2]=f2bf(x.z); o[3]=f2bf(x.w);
    o[4]=f2bf(y.x); o[5]=f2bf(y.y); o[6]=f2bf(y.z); o[7]=f2bf(y.w);
    *(bf16x8*)d = o;
}
__device__ __forceinline__ bf16x8 pack8(const float* __restrict__ s) {
    float4 x = *(const float4*)s;
    float4 y = *(const float4*)(s + 4);
    bf16x8 o;
    o[0]=f2bf(x.x); o[1]=f2bf(x.y); o[2]=f2bf(x.z); o[3]=f2bf(x.w);
    o[4]=f2bf(y.x); o[5]=f2bf(y.y); o[6]=f2bf(y.z); o[7]=f2bf(y.w);
    return o;
}
__device__ __forceinline__ bf16x8 pack2(const float4& x, const float4& y) {
    bf16x8 o;
    o[0]=f2bf(x.x); o[1]=f2bf(x.y); o[2]=f2bf(x.z); o[3]=f2bf(x.w);
    o[4]=f2bf(y.x); o[5]=f2bf(y.y); o[6]=f2bf(y.z); o[7]=f2bf(y.w);
    return o;
}

// One wave polls 64 per-block flags until all >= tgt.
__device__ __forceinline__ void poll_flags(const unsigned* fl, unsigned tgt) {
    const int lane = threadIdx.x & 63;
    unsigned f = __hip_atomic_load(&fl[lane], __ATOMIC_RELAXED,
                                   __HIP_MEMORY_SCOPE_AGENT);
    while (!__all((int)(f >= tgt))) {
        __builtin_amdgcn_s_sleep(2);
        f = __hip_atomic_load(&fl[lane], __ATOMIC_RELAXED,
                              __HIP_MEMORY_SCOPE_AGENT);
    }
}

// ---------------------------------------------------------------------------
// fp32 -> bf16 conversion: vid + W_ih1 (mega roles convert their own slices).
// ---------------------------------------------------------------------------
__global__ __launch_bounds__(256)
void cvt2(const float* __restrict__ vid,  short* __restrict__ vid_bf,
          const float* __restrict__ Wih1, short* __restrict__ Wih1_bf)
{
    const long b0 = 524288;            // vid   2048*2048/8
    const long b1 = b0 + 786432;       // W_ih1 3072*2048/8
    for (long i = (long)blockIdx.x * 256 + threadIdx.x; i < b1;
         i += (long)gridDim.x * 256) {
        if (i < b0) cvt8(vid + i * 8, vid_bf + i * 8);
        else { const long q = i - b0; cvt8(Wih1 + q * 8, Wih1_bf + q * 8); }
    }
}

// ---------------------------------------------------------------------------
// xp1 GEMM, fragment-linear LDS (conflict-free ds_read by construction).
// Writes xp1 T-MAJOR: output row m = t*64+b -> vid row = (m&63)*32 + (m>>6).
// 128x128 tile, BK=32, 4 waves (2x2 quadrants), grid (24, 16).
// ---------------------------------------------------------------------------
__global__ __launch_bounds__(256)
void gemm_xp1(const short* __restrict__ vid_bf,
              const short* __restrict__ Wih1_bf,
              const float* __restrict__ b_ih1,
              float* __restrict__ xp1)
{
    __shared__ __align__(16) short As[8 * 64 * 8];   // 8 KB, fragment order
    __shared__ __align__(16) short Bs[8 * 64 * 8];
    const int tid = threadIdx.x;
    const int w = tid >> 6, l = tid & 63;
    const int wm = w >> 1, wn = w & 1;
    const int lr = l & 15, lg = l >> 4;
    const int m0 = blockIdx.y * 128, n0 = blockIdx.x * 128;
    const int sr = tid >> 2;        // staging row 0..63 (+64 on 2nd issue)
    const int sc = tid & 3;         // staging k-group

    f32x4 acc[4][4] = {};

    for (int k0 = 0; k0 < Dv; k0 += 32) {
        #pragma unroll
        for (int i = 0; i < 2; ++i) {
            const int r = i * 64 + sr;                     // tile row 0..127
            const int m = m0 + r;
            const int arow = (m & 63) * Tt + (m >> 6);     // t-major -> vid row
            bf16x8 av = *(const bf16x8*)(vid_bf + (size_t)arow * Dv + k0 + sc * 8);
            bf16x8 bv = *(const bf16x8*)(Wih1_bf + (size_t)(n0 + r) * Dv + k0 + sc * 8);
            const int fi = (r >> 4) * 64 + sc * 16 + (r & 15);   // fragment slot
            *(bf16x8*)(As + fi * 8) = av;
            *(bf16x8*)(Bs + fi * 8) = bv;
        }
        __syncthreads();
        bf16x8 af[4], bfr[4];
        #pragma unroll
        for (int mt = 0; mt < 4; ++mt) {
            af[mt]  = *(const bf16x8*)(As + ((wm * 4 + mt) * 64 + l) * 8);
            bfr[mt] = *(const bf16x8*)(Bs + ((wn * 4 + mt) * 64 + l) * 8);
        }
        #pragma unroll
        for (int mt = 0; mt < 4; ++mt)
            #pragma unroll
            for (int nt = 0; nt < 4; ++nt)
                acc[mt][nt] = MFMA(af[mt], bfr[nt], acc[mt][nt]);
        __syncthreads();
    }

    #pragma unroll
    for (int mt = 0; mt < 4; ++mt)
        #pragma unroll
        for (int nt = 0; nt < 4; ++nt)
            #pragma unroll
            for (int v = 0; v < 4; ++v) {
                const int m = m0 + wm * 64 + mt * 16 + lg * 4 + v;
                const int n = n0 + wn * 64 + nt * 16 + lr;
                xp1[(size_t)m * G3 + n] = acc[mt][nt][v] + b_ih1[n];
            }
}

// ---------------------------------------------------------------------------
// MEGAKERNEL v2: encoder pipeline + decode GRU steps. 192 blocks = 3 roles.
//   role 0 (GRU1): t<32 xp from precomputed t-major xp1 (prefetched one round
//   ahead); t>=32 xp = b_ih1 broadcast. role 1 (proj), role 2 (GRU2) as r10.
// Roles stage their W slices fp32->bf16 in-register into LDS (frag-linear).
// ---------------------------------------------------------------------------
__global__ __launch_bounds__(256, 1)
void mega(const float* __restrict__ xp1, const float* __restrict__ b_ih1,
          const float* __restrict__ Whh1f, const float* __restrict__ b_hh1,
          const float* __restrict__ Wih2f, const float* __restrict__ b_ih2,
          const float* __restrict__ Whh2f, const float* __restrict__ b_hh2,
          short* __restrict__ out1h,   // (36,64,1024) bf16, slot0 = 0
          float* __restrict__ xp2s,    // (35,64,3072) fp32
          short* __restrict__ h2h,     // (36,64,1024) bf16, slot0 = 0
          unsigned* __restrict__ flags1, unsigned* __restrict__ flagsP,
          unsigned* __restrict__ flags2)
{
    __shared__ __align__(16) short Wl[4 * 3 * 8 * 64 * 8];   // 98304 B
    __shared__ __align__(16) float xch[4][4][3][256];        // 49152 B
    __shared__ __align__(16) short hstage[64][16];           // 2048 B
    const int tid = threadIdx.x;
    const int w  = tid >> 6;
    const int l  = tid & 63;
    const int lr = l & 15, lg = l >> 4;
    const int role = blockIdx.x >> 6;         // 0=GRU1, 1=proj, 2=GRU2
    const int k    = blockIdx.x & 63;
    const int j0 = k * 16;
    const int j  = j0 + lr;

    const float* Wf = (role == 0) ? Whh1f : (role == 1) ? Wih2f : Whh2f;
    const int ldw   = (role == 1) ? (Hd + 512) : Hd;
    const float* bias = (role == 0) ? b_hh1 : (role == 1) ? b_ih2 : b_hh2;

    // stage W slice into LDS, fp32 -> bf16 in-register, fragment-linear
    #pragma unroll
    for (int g = 0; g < 3; ++g)
        #pragma unroll
        for (int ks = 0; ks < 8; ++ks) {
            const float* src = Wf + (size_t)(g * Hd + j) * ldw + w * 256 + ks * 32 + lg * 8;
            *(bf16x8*)(Wl + ((((w * 3 + g) * 8 + ks) * 64) + l) * 8) = pack8(src);
        }

    const float b0 = bias[j], b1 = bias[Hd + j], b2 = bias[2 * Hd + j];
    short* Ab = (role == 2) ? h2h : out1h;

    float bxr = 0.f, bxz = 0.f, bxn = 0.f;
    float hp[4] = {0.f, 0.f, 0.f, 0.f};
    float xr[4], xz[4], xn[4];
    if (role == 0) {
        bxr = b_ih1[j]; bxz = b_ih1[Hd + j]; bxn = b_ih1[2 * Hd + j];
        #pragma unroll
        for (int v = 0; v < 4; ++v) {        // prefetch xp for t=0
            const int b = w * 16 + lg * 4 + v;
            const float* xrow = xp1 + (size_t)b * G3;    // t=0 row = b
            xr[v] = xrow[j]; xz[v] = xrow[Hd + j]; xn[v] = xrow[2 * Hd + j];
        }
    }
    __syncthreads();   // Wl ready

    for (int t = 0; t < TTOT; ++t) {
        if (role == 0)      { if (w == 0) poll_flags(flags1, (unsigned)t); }
        else if (role == 1) { if (w == 0) poll_flags(flags1, (unsigned)(t + 1)); }
        else {
            if (w == 0)      poll_flags(flagsP, (unsigned)(t + 1));
            else if (w == 1) poll_flags(flags2, (unsigned)t);
        }
        __syncthreads();
        asm volatile("" ::: "memory");

        const short* hin = Ab + (size_t)(role == 1 ? t + 1 : t) * (64 * Hd);
        bf16x8 A[4][8];
        #pragma unroll
        for (int mt = 0; mt < 4; ++mt)
            #pragma unroll
            for (int ks = 0; ks < 8; ++ks)
                A[mt][ks] = *(const bf16x8*)(hin + (size_t)(mt * 16 + lr) * Hd
                                             + w * 256 + ks * 32 + lg * 8);
        if (role == 2) {
            #pragma unroll
            for (int v = 0; v < 4; ++v) {
                const int b = w * 16 + lg * 4 + v;
                const float* xrow = xp2s + ((size_t)t * 64 + b) * G3;
                xr[v] = xrow[j]; xz[v] = xrow[Hd + j]; xn[v] = xrow[2 * Hd + j];
            }
        }

        f32x4 acc[4][3] = {};
        #pragma unroll
        for (int ks = 0; ks < 8; ++ks) {
            bf16x8 B0 = *(const bf16x8*)(Wl + ((((w * 3 + 0) * 8 + ks) * 64) + l) * 8);
            bf16x8 B1 = *(const bf16x8*)(Wl + ((((w * 3 + 1) * 8 + ks) * 64) + l) * 8);
            bf16x8 B2 = *(const bf16x8*)(Wl + ((((w * 3 + 2) * 8 + ks) * 64) + l) * 8);
            #pragma unroll
            for (int mt = 0; mt < 4; ++mt) {
                acc[mt][0] = MFMA(A[mt][ks], B0, acc[mt][0]);
                acc[mt][1] = MFMA(A[mt][ks], B1, acc[mt][1]);
                acc[mt][2] = MFMA(A[mt][ks], B2, acc[mt][2]);
            }
        }

        #pragma unroll
        for (int mt = 0; mt < 4; ++mt)
            #pragma unroll
            for (int g = 0; g < 3; ++g)
                *(f32x4*)&xch[w][mt][g][l * 4] = acc[mt][g];
        __syncthreads();
        f32x4 tot[3];
        #pragma unroll
        for (int g = 0; g < 3; ++g) {
            f32x4 t0 = *(const f32x4*)&xch[0][w][g][l * 4];
            f32x4 t1 = *(const f32x4*)&xch[1][w][g][l * 4];
            f32x4 t2 = *(const f32x4*)&xch[2][w][g][l * 4];
            f32x4 t3 = *(const f32x4*)&xch[3][w][g][l * 4];
            tot[g] = (t0 + t1) + (t2 + t3);
        }

        if (role == 1) {
            const float bg[3] = {b0, b1, b2};
            #pragma unroll
            for (int v = 0; v < 4; ++v) {
                const int b = w * 16 + lg * 4 + v;
                #pragma unroll
                for (int g = 0; g < 3; ++g) {
                    union { float f; unsigned u; } cv;
                    cv.f = tot[g][v] + bg[g];
                    __hip_atomic_store(
                        (unsigned*)(xp2s + ((size_t)t * 64 + b) * G3 + g * Hd + j),
                        cv.u, __ATOMIC_RELAXED, __HIP_MEMORY_SCOPE_AGENT);
                }
            }
            __syncthreads();
        } else {
            #pragma unroll
            for (int v = 0; v < 4; ++v) {
                const int b = w * 16 + lg * 4 + v;
                const float rg = 1.f / (1.f + __expf(-(xr[v] + tot[0][v] + b0)));
                const float zg = 1.f / (1.f + __expf(-(xz[v] + tot[1][v] + b1)));
                const float ng = tanhf(xn[v] + rg * (tot[2][v] + b2));
                const float hv = (1.f - zg) * ng + zg * hp[v];
                hp[v] = hv;
                hstage[b][lr] = f2bf(hv);
            }
            if (role == 0) {   // prefetch next round's xp (xp1 fully ready)
                if (t + 1 < Tt) {
                    #pragma unroll
                    for (int v = 0; v < 4; ++v) {
                        const int b = w * 16 + lg * 4 + v;
                        const float* xrow = xp1 + (size_t)((t + 1) * 64 + b) * G3;
                        xr[v] = xrow[j]; xz[v] = xrow[Hd + j]; xn[v] = xrow[2 * Hd + j];
                    }
                } else {
                    #pragma unroll
                    for (int v = 0; v < 4; ++v) { xr[v]=bxr; xz[v]=bxz; xn[v]=bxn; }
                }
            }
            __syncthreads();
            {
                const int b = tid >> 2, part = tid & 3;
                const u64 pv = *(const u64*)&hstage[b][part * 4];
                __hip_atomic_store(
                    (u64*)(Ab + (size_t)(t + 1) * (64 * Hd) + b * Hd + j0 + part * 4),
                    pv, __ATOMIC_RELAXED, __HIP_MEMORY_SCOPE_AGENT);
            }
            __syncthreads();
        }

        if (tid == 0) {
            unsigned* fl = (role == 0) ? flags1 : (role == 1) ? flagsP : flags2;
            __hip_atomic_store(&fl[k], (unsigned)(t + 1),
                               __ATOMIC_RELAXED, __HIP_MEMORY_SCOPE_AGENT);
        }
    }
}

// ---------------------------------------------------------------------------
// Logits GEMM v2: explicit 2-deep software pipeline on the fp32 W stream.
// Blocks 0..312: one W_obj pass computes decode steps 0 AND 2.
// Blocks 313..625: W_rel pass for step 1. One 16-col tile per wave.
// ---------------------------------------------------------------------------
__global__ __launch_bounds__(256)
void logits_dual(const short* __restrict__ h2h,
                 const float* __restrict__ Wobj, const float* __restrict__ bobj,
                 const float* __restrict__ Wrel, const float* __restrict__ brel,
                 float* __restrict__ logits3)
{
    const int tid = threadIdx.x;
    const int w = tid >> 6, l = tid & 63;
    const int lr = l & 15, lg = l >> 4;
    const bool dual = blockIdx.x < 313;
    const int nb = dual ? blockIdx.x : blockIdx.x - 313;
    const int tile = nb * 4 + w;
    if (tile >= NTILE) return;
    const int n0 = tile * 16;
    const float* Wo = dual ? Wobj : Wrel;
    const float* bo = dual ? bobj : brel;
    const short* hA = h2h + (size_t)33 * 64 * Hd;
    const short* hB = h2h + (size_t)34 * 64 * Hd;
    const short* hC = h2h + (size_t)35 * 64 * Hd;
    const short* h0 = dual ? hA : hB;

    f32x4 accA[4] = {}, accC[4] = {};
    const float* wbase = Wo + (size_t)(n0 + lr) * Hd + lg * 8;

    // 2-deep W ring buffer (raw float4; pack deferred to use point)
    float4 wx[2], wy[2];
    wx[0] = *(const float4*)(wbase);          wy[0] = *(const float4*)(wbase + 4);
    wx[1] = *(const float4*)(wbase + 32);     wy[1] = *(const float4*)(wbase + 36);

    #pragma unroll
    for (int ks = 0; ks < 32; ++ks) {
        const int bi = ks & 1;
        float4 nx = {}, ny = {};
        if (ks < 30) {
            nx = *(const float4*)(wbase + (ks + 2) * 32);
            ny = *(const float4*)(wbase + (ks + 2) * 32 + 4);
        }
        const bf16x8 wv = pack2(wx[bi], wy[bi]);
        #pragma unroll
        for (int mt = 0; mt < 4; ++mt) {
            bf16x8 a = *(const bf16x8*)(h0 + (size_t)(mt * 16 + lr) * Hd + ks * 32 + lg * 8);
            accA[mt] = MFMA(a, wv, accA[mt]);
        }
        if (dual) {
            #pragma unroll
            for (int mt = 0; mt < 4; ++mt) {
                bf16x8 c = *(const bf16x8*)(hC + (size_t)(mt * 16 + lr) * Hd + ks * 32 + lg * 8);
                accC[mt] = MFMA(c, wv, accC[mt]);
            }
        }
        if (ks < 30) { wx[bi] = nx; wy[bi] = ny; }
    }

    const float bn = bo[n0 + lr];
    float* lg0 = logits3 + (size_t)(dual ? 0 : 1) * 64 * Vv;
    float* lg2 = logits3 + (size_t)2 * 64 * Vv;
    #pragma unroll
    for (int mt = 0; mt < 4; ++mt)
        #pragma unroll
        for (int v = 0; v < 4; ++v) {
            const size_t row = (size_t)(mt * 16 + lg * 4 + v) * Vv + n0 + lr;
            lg0[row] = accA[mt][v] + bn;
            if (dual) lg2[row] = accC[mt][v] + bn;
        }
}

// ---------------------------------------------------------------------------
// Row log-softmax for all 3 steps: grid 192 = (step, batch).
// ---------------------------------------------------------------------------
__global__ __launch_bounds__(256)
void log_softmax_all(const float* __restrict__ logits3, float* __restrict__ out)
{
    __shared__ float red[4];
    const int step = blockIdx.x >> 6;
    const int b    = blockIdx.x & 63;
    const int tid  = threadIdx.x;
    const float* row = logits3 + ((size_t)step * 64 + b) * Vv;

    float m = -1e30f;
    for (int v = tid; v < Vv; v += 256) m = fmaxf(m, row[v]);
    #pragma unroll
    for (int off = 32; off > 0; off >>= 1) m = fmaxf(m, __shfl_down(m, off, 64));
    if ((tid & 63) == 0) red[tid >> 6] = m;
    __syncthreads();
    m = fmaxf(fmaxf(red[0], red[1]), fmaxf(red[2], red[3]));
    __syncthreads();

    float s = 0.f;
    for (int v = tid; v < Vv; v += 256) s += expf(row[v] - m);
    #pragma unroll
    for (int off = 32; off > 0; off >>= 1) s += __shfl_down(s, off, 64);
    if ((tid & 63) == 0) red[tid >> 6] = s;
    __syncthreads();
    s = red[0] + red[1] + red[2] + red[3];
    const float lse = m + logf(s);

    float* orow = out + ((size_t)b * ML + step) * Vv;
    for (int v = tid; v < Vv; v += 256) orow[v] = row[v] - lse;
}

// ---------------------------------------------------------------------------
extern "C" void kernel_launch(void* const* d_in, const int* in_sizes, int n_in,
                              void* d_out, int out_size, void* d_ws, size_t ws_size,
                              hipStream_t stream)
{
    (void)in_sizes; (void)n_in; (void)out_size; (void)ws_size;
    const float* vid   = (const float*)d_in[0];
    const float* W_ih1 = (const float*)d_in[1];
    const float* W_hh1 = (const float*)d_in[2];
    const float* b_ih1 = (const float*)d_in[3];
    const float* b_hh1 = (const float*)d_in[4];
    const float* W_ih2 = (const float*)d_in[5];   // (3072,1536); cols 0..1023 used
    const float* W_hh2 = (const float*)d_in[6];
    const float* b_ih2 = (const float*)d_in[7];
    const float* b_hh2 = (const float*)d_in[8];
    const float* W_obj = (const float*)d_in[9];
    const float* b_obj = (const float*)d_in[10];
    const float* W_rel = (const float*)d_in[11];
    const float* b_rel = (const float*)d_in[12];
    float* out = (float*)d_out;

    // workspace carve-up (~98 MB)
    char* p = (char*)d_ws;
    short* vid_bf   = (short*)p; p += (size_t)2048 * Dv * 2;        // 8.0 MB
    short* Wih1_bf  = (short*)p; p += (size_t)G3 * Dv * 2;          // 12.6 MB
    unsigned int* flg = (unsigned int*)p; p += 4096;
    short* out1h  = (short*)p; p += (size_t)36 * 64 * Hd * 2;       // 4.7 MB
    short* h2h    = (short*)p; p += (size_t)36 * 64 * Hd * 2;       // 4.7 MB
    float* xp1    = (float*)p; p += (size_t)2048 * G3 * 4;          // 25.2 MB (t-major)
    float* xp2s   = (float*)p; p += (size_t)TTOT * 64 * G3 * 4;     // 27.5 MB
    float* logits3= (float*)p; p += (size_t)ML * 64 * Vv * 4;       // 15.4 MB

    unsigned* flags1 = flg;
    unsigned* flagsP = flg + 64;
    unsigned* flags2 = flg + 128;

    hipMemsetAsync(flg, 0, 4096, stream);
    hipMemsetAsync(out1h, 0, (size_t)64 * Hd * 2, stream);   // slot 0 = h1(-1)=0
    hipMemsetAsync(h2h,   0, (size_t)64 * Hd * 2, stream);   // slot 0 = h2(-1)=0

    // convert vid + W_ih1 (recurrent/projection weights converted in mega)
    cvt2<<<640, 256, 0, stream>>>(vid, vid_bf, W_ih1, Wih1_bf);

    // xp1 = vid @ W_ih1^T + b_ih1, written t-major (conflict-free LDS GEMM)
    gemm_xp1<<<dim3(G3 / 128, 2048 / 128), 256, 0, stream>>>(
        vid_bf, Wih1_bf, b_ih1, xp1);

    // megakernel: encoder pipeline + decode GRU steps (192 blocks)
    mega<<<192, 256, 0, stream>>>(
        xp1, b_ih1, W_hh1, b_hh1, W_ih2, b_ih2, W_hh2, b_hh2,
        out1h, xp2s, h2h, flags1, flagsP, flags2);

    // logits for all 3 decode steps (one W_obj pass covers steps 0 and 2)
    logits_dual<<<626, 256, 0, stream>>>(h2h, W_obj, b_obj, W_rel, b_rel, logits3);

    // log-softmax -> d_out
    log_softmax_all<<<192, 256, 0, stream>>>(logits3, out);
}